// Round 1
// baseline (1452.965 us; speedup 1.0000x reference)
//
#include <hip/hip_runtime.h>
#include <math.h>

// Problem constants (B=16, C=L=256 scan axis, dm=di=1024, n=2, dtr=64, k=4)
#define BATCH 16
#define LSEQ  256
#define DM    1024
#define DI    1024
#define NROWS (BATCH*LSEQ)   // 4096
#define DTR   64
#define NDBL  68             // dtr + 2*n
#define TWO_DI 2048

__device__ __forceinline__ float siluf(float x) {
    return x / (1.0f + __expf(-x));
}
__device__ __forceinline__ float softplusf(float x) {
    // log1p(exp(x)), stable
    return fmaxf(x, 0.0f) + log1pf(__expf(-fabsf(x)));
}

// ---------------------------------------------------------------------------
// gemm_nt: C[M,N] = A[M,K] @ W[N,K]^T  (both row-major), 64x64x16 tiles,
// 256 threads, 4x4 microtile. M must be a multiple of 64; K a multiple of 16.
// N may be ragged (guarded). EP: 0=none, 1=softplus(v+bias[c]), 2=silu(v+bias[c])
// ---------------------------------------------------------------------------
template <int EP>
__global__ __launch_bounds__(256) void gemm_nt(
    const float* __restrict__ A, int lda,
    const float* __restrict__ W, int ldw,
    const float* __restrict__ bias,
    float* __restrict__ C, int ldc,
    int M, int N, int K)
{
    __shared__ float As[16][64];  // As[kk][i]  = A[row0+i][k0+kk]
    __shared__ float Ws[16][64];  // Ws[kk][j]  = W[col0+j][k0+kk]

    const int tid = threadIdx.x;
    const int tx = tid & 15;        // 0..15  -> col group
    const int ty = tid >> 4;        // 0..15  -> row group
    const int row0 = blockIdx.y * 64;
    const int col0 = blockIdx.x * 64;

    const int lrow = tid >> 2;        // 0..63
    const int lcol = (tid & 3) * 4;   // 0,4,8,12

    float acc[4][4] = {};

    for (int k0 = 0; k0 < K; k0 += 16) {
        // A tile (rows always in-bounds: M % 64 == 0 guaranteed by caller)
        const float4 av = *(const float4*)(A + (size_t)(row0 + lrow) * lda + k0 + lcol);
        As[lcol + 0][lrow] = av.x;
        As[lcol + 1][lrow] = av.y;
        As[lcol + 2][lrow] = av.z;
        As[lcol + 3][lrow] = av.w;
        // W tile (guard ragged N)
        float4 wv = make_float4(0.f, 0.f, 0.f, 0.f);
        const int wrow = col0 + lrow;
        if (wrow < N) wv = *(const float4*)(W + (size_t)wrow * ldw + k0 + lcol);
        Ws[lcol + 0][lrow] = wv.x;
        Ws[lcol + 1][lrow] = wv.y;
        Ws[lcol + 2][lrow] = wv.z;
        Ws[lcol + 3][lrow] = wv.w;
        __syncthreads();

        #pragma unroll
        for (int kk = 0; kk < 16; kk++) {
            const float4 a = *(const float4*)&As[kk][ty * 4];
            const float4 b = *(const float4*)&Ws[kk][tx * 4];
            const float af[4] = {a.x, a.y, a.z, a.w};
            const float bf[4] = {b.x, b.y, b.z, b.w};
            #pragma unroll
            for (int i = 0; i < 4; i++)
                #pragma unroll
                for (int j = 0; j < 4; j++)
                    acc[i][j] = fmaf(af[i], bf[j], acc[i][j]);
        }
        __syncthreads();
    }

    #pragma unroll
    for (int i = 0; i < 4; i++) {
        const int r = row0 + ty * 4 + i;
        #pragma unroll
        for (int j = 0; j < 4; j++) {
            const int c = col0 + tx * 4 + j;
            if (c < N) {
                float v = acc[i][j];
                if (EP == 1) v = softplusf(v + bias[c]);
                else if (EP == 2) v = siluf(v + bias[c]);
                C[(size_t)r * ldc + c] = v;
            }
        }
    }
}

// ---------------------------------------------------------------------------
// gemm_nn_silu (batched): C[b][M,N] = silu( Wm[M,K] @ X[b][K,N] )
// Wm shared across batch. M,N multiples of 64, K multiple of 16.
// ---------------------------------------------------------------------------
__global__ __launch_bounds__(256) void gemm_nn_silu(
    const float* __restrict__ Wm,   // (M,K) row-major
    const float* __restrict__ X,    // (B,K,N)
    float* __restrict__ C,          // (B,M,N)
    int M, int N, int K)
{
    const int bz = blockIdx.z;
    const float* Xb = X + (size_t)bz * K * N;
    float* Cb = C + (size_t)bz * M * N;

    __shared__ float As[16][64];  // As[kk][i] = Wm[row0+i][k0+kk]
    __shared__ float Bs[16][64];  // Bs[kk][j] = Xb[k0+kk][col0+j]

    const int tid = threadIdx.x;
    const int tx = tid & 15;
    const int ty = tid >> 4;
    const int row0 = blockIdx.y * 64;
    const int col0 = blockIdx.x * 64;

    const int lrow = tid >> 2;        // for Wm loads
    const int lcol = (tid & 3) * 4;
    const int bk = tid >> 4;          // 0..15: k row of B tile
    const int bn = (tid & 15) * 4;    // 0..60: n offset

    float acc[4][4] = {};

    for (int k0 = 0; k0 < K; k0 += 16) {
        const float4 av = *(const float4*)(Wm + (size_t)(row0 + lrow) * K + k0 + lcol);
        As[lcol + 0][lrow] = av.x;
        As[lcol + 1][lrow] = av.y;
        As[lcol + 2][lrow] = av.z;
        As[lcol + 3][lrow] = av.w;
        const float4 xv = *(const float4*)(Xb + (size_t)(k0 + bk) * N + col0 + bn);
        *(float4*)&Bs[bk][bn] = xv;
        __syncthreads();

        #pragma unroll
        for (int kk = 0; kk < 16; kk++) {
            const float4 a = *(const float4*)&As[kk][ty * 4];
            const float4 b = *(const float4*)&Bs[kk][tx * 4];
            const float af[4] = {a.x, a.y, a.z, a.w};
            const float bf[4] = {b.x, b.y, b.z, b.w};
            #pragma unroll
            for (int i = 0; i < 4; i++)
                #pragma unroll
                for (int j = 0; j < 4; j++)
                    acc[i][j] = fmaf(af[i], bf[j], acc[i][j]);
        }
        __syncthreads();
    }

    #pragma unroll
    for (int i = 0; i < 4; i++) {
        const int r = row0 + ty * 4 + i;
        #pragma unroll
        for (int j = 0; j < 4; j++) {
            const int c = col0 + tx * 4 + j;
            Cb[(size_t)r * N + c] = siluf(acc[i][j]);
        }
    }
}

// ---------------------------------------------------------------------------
// Depthwise causal conv (k=4) along l + bias + SiLU.
// Input: xz (4096, 2048) — uses first DI columns. Output xi (4096, 1024).
// ---------------------------------------------------------------------------
__global__ __launch_bounds__(256) void conv_silu(
    const float* __restrict__ xz,
    const float* __restrict__ convw,   // (DI,1,4)
    const float* __restrict__ convb,   // (DI)
    float* __restrict__ xi)
{
    const int r = blockIdx.x;          // 0..4095
    const int l = r & (LSEQ - 1);
    for (int d = threadIdx.x; d < DI; d += 256) {
        const float w0 = convw[d * 4 + 0];
        const float w1 = convw[d * 4 + 1];
        const float w2 = convw[d * 4 + 2];
        const float w3 = convw[d * 4 + 3];
        float acc = w3 * xz[(size_t)r * TWO_DI + d];
        if (l >= 1) acc = fmaf(w2, xz[(size_t)(r - 1) * TWO_DI + d], acc);
        if (l >= 2) acc = fmaf(w1, xz[(size_t)(r - 2) * TWO_DI + d], acc);
        if (l >= 3) acc = fmaf(w0, xz[(size_t)(r - 3) * TWO_DI + d], acc);
        xi[(size_t)r * DI + d] = siluf(acc + convb[d]);
    }
}

// ---------------------------------------------------------------------------
// Selective scan over l (n=2 states), fused with D-skip and z-gate.
// One thread per (b,d). Grid: (DI/256, BATCH).
// ---------------------------------------------------------------------------
__global__ __launch_bounds__(256) void scan_kernel(
    const float* __restrict__ dt,    // (4096,1024)
    const float* __restrict__ xi,    // (4096,1024)
    const float* __restrict__ xz,    // (4096,2048): z = cols [1024,2048)
    const float* __restrict__ dbl,   // (4096,68): cols 64..67 = B0,B1,C0,C1
    const float* __restrict__ Alog,  // (1024,2)
    const float* __restrict__ Dp,    // (1024)
    float* __restrict__ yg)          // (4096,1024)
{
    const int d = blockIdx.x * 256 + threadIdx.x;
    const int b = blockIdx.y;
    const float A0 = -__expf(Alog[d * 2 + 0]);
    const float A1 = -__expf(Alog[d * 2 + 1]);
    const float Dv = Dp[d];
    float h0 = 0.f, h1 = 0.f;
    const int rbase = b * LSEQ;
    for (int l = 0; l < LSEQ; l++) {
        const int r = rbase + l;
        const float dtv = dt[(size_t)r * DI + d];
        const float xiv = xi[(size_t)r * DI + d];
        const float B0 = dbl[r * NDBL + 64];
        const float B1 = dbl[r * NDBL + 65];
        const float C0 = dbl[r * NDBL + 66];
        const float C1 = dbl[r * NDBL + 67];
        const float zv = xz[(size_t)r * TWO_DI + DI + d];
        const float dbx = dtv * xiv;
        h0 = fmaf(__expf(dtv * A0), h0, dbx * B0);
        h1 = fmaf(__expf(dtv * A1), h1, dbx * B1);
        const float y = fmaf(h0, C0, fmaf(h1, C1, Dv * xiv));
        yg[(size_t)r * DI + d] = y * siluf(zv);
    }
}

// ---------------------------------------------------------------------------
// LayerNorm over last dim (1024), in-place. One block (256 thr) per row.
// ---------------------------------------------------------------------------
__global__ __launch_bounds__(256) void ln_kernel(
    float* __restrict__ s,
    const float* __restrict__ g,
    const float* __restrict__ bb)
{
    __shared__ float red[8];
    const size_t base = (size_t)blockIdx.x * DM;
    const int t = threadIdx.x;
    float x0 = s[base + t];
    float x1 = s[base + t + 256];
    float x2 = s[base + t + 512];
    float x3 = s[base + t + 768];
    float sum = x0 + x1 + x2 + x3;
    #pragma unroll
    for (int o = 32; o; o >>= 1) sum += __shfl_down(sum, o, 64);
    const int w = t >> 6, lane = t & 63;
    if (lane == 0) red[w] = sum;
    __syncthreads();
    const float m = (red[0] + red[1] + red[2] + red[3]) * (1.0f / 1024.0f);
    const float d0 = x0 - m, d1 = x1 - m, d2 = x2 - m, d3 = x3 - m;
    float ss = d0 * d0 + d1 * d1 + d2 * d2 + d3 * d3;
    #pragma unroll
    for (int o = 32; o; o >>= 1) ss += __shfl_down(ss, o, 64);
    if (lane == 0) red[4 + w] = ss;
    __syncthreads();
    const float var = (red[4] + red[5] + red[6] + red[7]) * (1.0f / 1024.0f);
    const float inv = rsqrtf(var + 1e-5f);
    s[base + t]       = d0 * inv * g[t]       + bb[t];
    s[base + t + 256] = d1 * inv * g[t + 256] + bb[t + 256];
    s[base + t + 512] = d2 * inv * g[t + 512] + bb[t + 512];
    s[base + t + 768] = d3 * inv * g[t + 768] + bb[t + 768];
}

// out = silu(s + out), elementwise
__global__ __launch_bounds__(256) void final_silu(
    const float* __restrict__ s, float* __restrict__ out)
{
    const size_t i = (size_t)blockIdx.x * 256 + threadIdx.x;
    out[i] = siluf(s[i] + out[i]);
}

// ---------------------------------------------------------------------------
extern "C" void kernel_launch(void* const* d_in, const int* in_sizes, int n_in,
                              void* d_out, int out_size, void* d_ws, size_t ws_size,
                              hipStream_t stream)
{
    const float* x        = (const float*)d_in[0];   // (16,256,32,32) == (16,256,1024)
    const float* m1_Win   = (const float*)d_in[1];
    const float* m1_convw = (const float*)d_in[2];
    const float* m1_convb = (const float*)d_in[3];
    const float* m1_Wx    = (const float*)d_in[4];
    const float* m1_Wdt   = (const float*)d_in[5];
    const float* m1_bdt   = (const float*)d_in[6];
    const float* m1_Alog  = (const float*)d_in[7];
    const float* m1_D     = (const float*)d_in[8];
    const float* m1_Wout  = (const float*)d_in[9];
    const float* m2_Win   = (const float*)d_in[10];
    const float* m2_convw = (const float*)d_in[11];
    const float* m2_convb = (const float*)d_in[12];
    const float* m2_Wx    = (const float*)d_in[13];
    const float* m2_Wdt   = (const float*)d_in[14];
    const float* m2_bdt   = (const float*)d_in[15];
    const float* m2_Alog  = (const float*)d_in[16];
    const float* m2_D     = (const float*)d_in[17];
    const float* m2_Wout  = (const float*)d_in[18];
    const float* ln1_g    = (const float*)d_in[19];
    const float* ln1_b    = (const float*)d_in[20];
    const float* ln2_g    = (const float*)d_in[21];
    const float* ln2_b    = (const float*)d_in[22];
    const float* W_mid    = (const float*)d_in[23];
    const float* W_spa    = (const float*)d_in[24];
    const float* b_spa    = (const float*)d_in[25];
    const float* W_res    = (const float*)d_in[26];

    float* ws = (float*)d_ws;
    size_t off = 0;
    float* buf_xz  = ws + off; off += (size_t)NROWS * TWO_DI;  // 8388608
    float* buf_xi  = ws + off; off += (size_t)NROWS * DI;      // 4194304
    float* buf_dbl = ws + off; off += (size_t)NROWS * NDBL;    // 278528
    float* buf_dt  = ws + off; off += (size_t)NROWS * DI;
    float* buf_y   = ws + off; off += (size_t)NROWS * DI;
    float* buf_s   = ws + off; off += (size_t)NROWS * DI;
    float* buf_t   = ws + off; off += (size_t)NROWS * DI;
    (void)ws_size; (void)n_in; (void)in_sizes; (void)out_size;

    const dim3 blk(256);

    auto mamba = [&](const float* inp, const float* Win, const float* convw,
                     const float* convb, const float* Wx, const float* Wdt,
                     const float* bdt, const float* Alog, const float* Dp,
                     const float* Wout, float* out_buf) {
        // xz = inp @ Win.T  : (4096,2048)
        gemm_nt<0><<<dim3(TWO_DI / 64, NROWS / 64), blk, 0, stream>>>(
            inp, DM, Win, DM, nullptr, buf_xz, TWO_DI, NROWS, TWO_DI, DM);
        // causal depthwise conv + silu -> xi (4096,1024)
        conv_silu<<<dim3(NROWS), blk, 0, stream>>>(buf_xz, convw, convb, buf_xi);
        // dbl = xi @ Wx.T : (4096,68)
        gemm_nt<0><<<dim3(2, NROWS / 64), blk, 0, stream>>>(
            buf_xi, DI, Wx, DI, nullptr, buf_dbl, NDBL, NROWS, NDBL, DI);
        // dt = softplus(dbl[:, :64] @ Wdt.T + bdt) : (4096,1024)
        gemm_nt<1><<<dim3(DI / 64, NROWS / 64), blk, 0, stream>>>(
            buf_dbl, NDBL, Wdt, DTR, bdt, buf_dt, DI, NROWS, DI, DTR);
        // scan + D-skip + z-gate -> yg (4096,1024)
        scan_kernel<<<dim3(DI / 256, BATCH), blk, 0, stream>>>(
            buf_dt, buf_xi, buf_xz, buf_dbl, Alog, Dp, buf_y);
        // out = yg @ Wout.T : (4096,1024)
        gemm_nt<0><<<dim3(DM / 64, NROWS / 64), blk, 0, stream>>>(
            buf_y, DI, Wout, DI, nullptr, out_buf, DM, NROWS, DM, DI);
    };

    // ---- Mamba 1 + LN1 ----
    mamba(x, m1_Win, m1_convw, m1_convb, m1_Wx, m1_Wdt, m1_bdt, m1_Alog, m1_D,
          m1_Wout, buf_s);
    ln_kernel<<<dim3(NROWS), blk, 0, stream>>>(buf_s, ln1_g, ln1_b);

    // ---- channel mix: buf_t[b] = silu(W_mid @ buf_s[b]) ----
    gemm_nn_silu<<<dim3(DM / 64, LSEQ / 64, BATCH), blk, 0, stream>>>(
        W_mid, buf_s, buf_t, LSEQ, DM, LSEQ);

    // ---- Mamba 2 + LN2 ----
    mamba(buf_t, m2_Win, m2_convw, m2_convb, m2_Wx, m2_Wdt, m2_bdt, m2_Alog,
          m2_D, m2_Wout, buf_s);
    ln_kernel<<<dim3(NROWS), blk, 0, stream>>>(buf_s, ln2_g, ln2_b);

    // ---- residual path: buf_t = silu(x @ W_spa.T + b_spa)  (buf_t free now) ----
    gemm_nt<2><<<dim3(DM / 64, NROWS / 64), blk, 0, stream>>>(
        x, DM, W_spa, DM, b_spa, buf_t, DM, NROWS, DM, DM);
    // r2 = silu(W_res @ r) per batch -> stage into d_out
    gemm_nn_silu<<<dim3(DM / 64, LSEQ / 64, BATCH), blk, 0, stream>>>(
        W_res, buf_t, (float*)d_out, LSEQ, DM, LSEQ);

    // ---- out = silu(s2 + r2) ----
    final_silu<<<dim3((NROWS * DM) / 256), blk, 0, stream>>>(
        buf_s, (float*)d_out);
}

// Round 2
// 739.404 us; speedup vs baseline: 1.9650x; 1.9650x over previous
//
#include <hip/hip_runtime.h>
#include <math.h>

// Problem constants (B=16, L=C=256 scan axis, dm=di=1024, n=2, dtr=64, k=4)
#define BATCH 16
#define LSEQ  256
#define DM    1024
#define DI    1024
#define NROWS (BATCH*LSEQ)   // 4096
#define DTR   64
#define NDBL  68             // dtr + 2*n
#define TWO_DI 2048

typedef __attribute__((ext_vector_type(8))) short short8;
typedef __attribute__((ext_vector_type(4))) float floatx4;

__device__ __forceinline__ float siluf(float x) {
    return x / (1.0f + __expf(-x));
}
__device__ __forceinline__ float softplusf(float x) {
    return fmaxf(x, 0.0f) + log1pf(__expf(-fabsf(x)));
}
// fp32 -> bf16 (RNE), raw bits
__device__ __forceinline__ unsigned short f2bf(float f) {
    unsigned int u = __float_as_uint(f);
    u += 0x7fffu + ((u >> 16) & 1u);
    return (unsigned short)(u >> 16);
}
// async global->LDS, 16B per lane; LDS dest = wave-uniform base + lane*16
__device__ __forceinline__ void async16(const short* g, short* l) {
    __builtin_amdgcn_global_load_lds(
        (const __attribute__((address_space(1))) unsigned int*)g,
        (__attribute__((address_space(3))) unsigned int*)l,
        16, 0, 0);
}

// ---------------------------------------------------------------------------
// cast fp32 -> bf16, 4 elts/thread. n multiple of 1024.
// ---------------------------------------------------------------------------
__global__ __launch_bounds__(256) void cast_bf16(
    const float* __restrict__ in, unsigned short* __restrict__ out)
{
    const size_t i = ((size_t)blockIdx.x * 256 + threadIdx.x) * 4;
    const float4 v = *(const float4*)(in + i);
    union { unsigned short s[4]; unsigned long long u; } p;
    p.s[0] = f2bf(v.x); p.s[1] = f2bf(v.y);
    p.s[2] = f2bf(v.z); p.s[3] = f2bf(v.w);
    *(unsigned long long*)(out + i) = p.u;
}

// ---------------------------------------------------------------------------
// bf16 MFMA GEMM (nt): C[M,N] = A[M,K] @ W[N,K]^T, fp32 out.
// A,W bf16 row-major. M%128==0, N%128==0, K%32==0.
// 256 thr = 4 waves in 2x2; 128x128 tile; BK=32; 16x16x32 MFMA, 4x4 per wave.
// EP: 0=none, 2=silu(v+bias[c])
// ---------------------------------------------------------------------------
template <int EP>
__global__ __launch_bounds__(256) void gemm_bf16_nt(
    const short* __restrict__ A,
    const short* __restrict__ W,
    const float* __restrict__ bias,
    float* __restrict__ C,
    int M, int N, int K)
{
    __shared__ short As[128 * 32];   // [m][k], stride 32 elts (64 B)
    __shared__ short Bs[128 * 32];   // [n][k]

    const int tid  = threadIdx.x;
    const int wave = tid >> 6;
    const int lane = tid & 63;
    const int wm = wave >> 1;        // 0..1
    const int wn = wave & 1;         // 0..1
    const int row0 = blockIdx.y * 128;
    const int col0 = blockIdx.x * 128;

    // staging: each wave stages 32 rows of A and 32 rows of B (2 calls each)
    const int srow  = lane >> 2;         // 0..15
    const int skoff = (lane & 3) * 8;    // k elts
    const short* gA0 = A + (size_t)(row0 + wave * 32 + srow) * K + skoff;
    const short* gA1 = gA0 + (size_t)16 * K;
    const short* gB0 = W + (size_t)(col0 + wave * 32 + srow) * K + skoff;
    const short* gB1 = gB0 + (size_t)16 * K;
    short* lA0 = As + (wave * 32) * 32;
    short* lA1 = lA0 + 16 * 32;
    short* lB0 = Bs + (wave * 32) * 32;
    short* lB1 = lB0 + 16 * 32;

    const int fr = lane & 15;            // frag row (m or n)
    const int fk = (lane >> 4) * 8;      // frag k offset

    floatx4 acc[4][4] = {};

    for (int k0 = 0; k0 < K; k0 += 32) {
        async16(gA0 + k0, lA0);
        async16(gA1 + k0, lA1);
        async16(gB0 + k0, lB0);
        async16(gB1 + k0, lB1);
        __syncthreads();

        short8 af[4], bfr[4];
        #pragma unroll
        for (int t = 0; t < 4; t++) {
            af[t]  = *(const short8*)&As[(wm * 64 + t * 16 + fr) * 32 + fk];
            bfr[t] = *(const short8*)&Bs[(wn * 64 + t * 16 + fr) * 32 + fk];
        }
        #pragma unroll
        for (int i = 0; i < 4; i++)
            #pragma unroll
            for (int j = 0; j < 4; j++)
                acc[i][j] = __builtin_amdgcn_mfma_f32_16x16x32_bf16(
                    af[i], bfr[j], acc[i][j], 0, 0, 0);
        __syncthreads();
    }

    // C/D layout: col = lane&15, row = (lane>>4)*4 + r
    const int crow = row0 + wm * 64 + (lane >> 4) * 4;
    const int ccol = col0 + wn * 64 + (lane & 15);
    #pragma unroll
    for (int i = 0; i < 4; i++) {
        #pragma unroll
        for (int j = 0; j < 4; j++) {
            const int c = ccol + j * 16;
            float* cp = C + (size_t)(crow + i * 16) * N + c;
            #pragma unroll
            for (int r = 0; r < 4; r++) {
                float v = acc[i][j][r];
                if (EP == 2) v = siluf(v + bias[c]);
                cp[(size_t)r * N] = v;
            }
        }
    }
}

// ---------------------------------------------------------------------------
// fp32 gemm_nt (small GEMMs): C[M,N] = A[M,K] @ W[N,K]^T
// EP: 0=none, 1=softplus(v+bias[c])
// ---------------------------------------------------------------------------
template <int EP>
__global__ __launch_bounds__(256) void gemm_nt(
    const float* __restrict__ A, int lda,
    const float* __restrict__ W, int ldw,
    const float* __restrict__ bias,
    float* __restrict__ C, int ldc,
    int M, int N, int K)
{
    __shared__ float Asf[16][64];
    __shared__ float Wsf[16][64];

    const int tid = threadIdx.x;
    const int tx = tid & 15;
    const int ty = tid >> 4;
    const int row0 = blockIdx.y * 64;
    const int col0 = blockIdx.x * 64;
    const int lrow = tid >> 2;
    const int lcol = (tid & 3) * 4;

    float acc[4][4] = {};

    for (int k0 = 0; k0 < K; k0 += 16) {
        const float4 av = *(const float4*)(A + (size_t)(row0 + lrow) * lda + k0 + lcol);
        Asf[lcol + 0][lrow] = av.x;
        Asf[lcol + 1][lrow] = av.y;
        Asf[lcol + 2][lrow] = av.z;
        Asf[lcol + 3][lrow] = av.w;
        float4 wv = make_float4(0.f, 0.f, 0.f, 0.f);
        const int wrow = col0 + lrow;
        if (wrow < N) wv = *(const float4*)(W + (size_t)wrow * ldw + k0 + lcol);
        Wsf[lcol + 0][lrow] = wv.x;
        Wsf[lcol + 1][lrow] = wv.y;
        Wsf[lcol + 2][lrow] = wv.z;
        Wsf[lcol + 3][lrow] = wv.w;
        __syncthreads();

        #pragma unroll
        for (int kk = 0; kk < 16; kk++) {
            const float4 a = *(const float4*)&Asf[kk][ty * 4];
            const float4 b = *(const float4*)&Wsf[kk][tx * 4];
            const float af[4] = {a.x, a.y, a.z, a.w};
            const float bfv[4] = {b.x, b.y, b.z, b.w};
            #pragma unroll
            for (int i = 0; i < 4; i++)
                #pragma unroll
                for (int j = 0; j < 4; j++)
                    acc[i][j] = fmaf(af[i], bfv[j], acc[i][j]);
        }
        __syncthreads();
    }

    #pragma unroll
    for (int i = 0; i < 4; i++) {
        const int r = row0 + ty * 4 + i;
        #pragma unroll
        for (int j = 0; j < 4; j++) {
            const int c = col0 + tx * 4 + j;
            if (c < N) {
                float v = acc[i][j];
                if (EP == 1) v = softplusf(v + bias[c]);
                C[(size_t)r * ldc + c] = v;
            }
        }
    }
}

// ---------------------------------------------------------------------------
// fp32 batched nn GEMM: C[b][M,N] = silu( Wm[M,K] @ X[b][K,N] )
// OUT16: 1 -> write bf16 (ushort), 0 -> fp32
// ---------------------------------------------------------------------------
template <int OUT16>
__global__ __launch_bounds__(256) void gemm_nn_silu(
    const float* __restrict__ Wm,
    const float* __restrict__ X,
    void* __restrict__ Cout,
    int M, int N, int K)
{
    const int bz = blockIdx.z;
    const float* Xb = X + (size_t)bz * K * N;

    __shared__ float Asf[16][64];
    __shared__ float Bsf[16][64];

    const int tid = threadIdx.x;
    const int tx = tid & 15;
    const int ty = tid >> 4;
    const int row0 = blockIdx.y * 64;
    const int col0 = blockIdx.x * 64;
    const int lrow = tid >> 2;
    const int lcol = (tid & 3) * 4;
    const int bk = tid >> 4;
    const int bn = (tid & 15) * 4;

    float acc[4][4] = {};

    for (int k0 = 0; k0 < K; k0 += 16) {
        const float4 av = *(const float4*)(Wm + (size_t)(row0 + lrow) * K + k0 + lcol);
        Asf[lcol + 0][lrow] = av.x;
        Asf[lcol + 1][lrow] = av.y;
        Asf[lcol + 2][lrow] = av.z;
        Asf[lcol + 3][lrow] = av.w;
        *(float4*)&Bsf[bk][bn] = *(const float4*)(Xb + (size_t)(k0 + bk) * N + col0 + bn);
        __syncthreads();

        #pragma unroll
        for (int kk = 0; kk < 16; kk++) {
            const float4 a = *(const float4*)&Asf[kk][ty * 4];
            const float4 b = *(const float4*)&Bsf[kk][tx * 4];
            const float af[4] = {a.x, a.y, a.z, a.w};
            const float bfv[4] = {b.x, b.y, b.z, b.w};
            #pragma unroll
            for (int i = 0; i < 4; i++)
                #pragma unroll
                for (int j = 0; j < 4; j++)
                    acc[i][j] = fmaf(af[i], bfv[j], acc[i][j]);
        }
        __syncthreads();
    }

    #pragma unroll
    for (int i = 0; i < 4; i++) {
        const int r = row0 + ty * 4 + i;
        #pragma unroll
        for (int j = 0; j < 4; j++) {
            const int c = col0 + tx * 4 + j;
            const float v = siluf(acc[i][j]);
            if (OUT16)
                ((unsigned short*)Cout)[(size_t)bz * M * N + (size_t)r * N + c] = f2bf(v);
            else
                ((float*)Cout)[(size_t)bz * M * N + (size_t)r * N + c] = v;
        }
    }
}

// ---------------------------------------------------------------------------
// Depthwise causal conv (k=4) + bias + SiLU. Writes fp32 xi and bf16 xi16.
// ---------------------------------------------------------------------------
__global__ __launch_bounds__(256) void conv_silu(
    const float* __restrict__ xz,
    const float* __restrict__ convw,
    const float* __restrict__ convb,
    float* __restrict__ xi,
    unsigned short* __restrict__ xi16)
{
    const int r = blockIdx.x;
    const int l = r & (LSEQ - 1);
    for (int d = threadIdx.x; d < DI; d += 256) {
        const float w0 = convw[d * 4 + 0];
        const float w1 = convw[d * 4 + 1];
        const float w2 = convw[d * 4 + 2];
        const float w3 = convw[d * 4 + 3];
        float acc = w3 * xz[(size_t)r * TWO_DI + d];
        if (l >= 1) acc = fmaf(w2, xz[(size_t)(r - 1) * TWO_DI + d], acc);
        if (l >= 2) acc = fmaf(w1, xz[(size_t)(r - 2) * TWO_DI + d], acc);
        if (l >= 3) acc = fmaf(w0, xz[(size_t)(r - 3) * TWO_DI + d], acc);
        const float v = siluf(acc + convb[d]);
        xi[(size_t)r * DI + d] = v;
        xi16[(size_t)r * DI + d] = f2bf(v);
    }
}

// ---------------------------------------------------------------------------
// Selective scan (n=2), fused D-skip + z-gate, bf16 output.
// ---------------------------------------------------------------------------
__global__ __launch_bounds__(256) void scan_kernel(
    const float* __restrict__ dt,
    const float* __restrict__ xi,
    const float* __restrict__ xz,    // z = cols [1024,2048)
    const float* __restrict__ dbl,   // cols 64..67 = B0,B1,C0,C1
    const float* __restrict__ Alog,
    const float* __restrict__ Dp,
    unsigned short* __restrict__ yg16)
{
    const int d = blockIdx.x * 256 + threadIdx.x;
    const int b = blockIdx.y;
    const float A0 = -__expf(Alog[d * 2 + 0]);
    const float A1 = -__expf(Alog[d * 2 + 1]);
    const float Dv = Dp[d];
    float h0 = 0.f, h1 = 0.f;
    const int rbase = b * LSEQ;
    for (int l = 0; l < LSEQ; l++) {
        const int r = rbase + l;
        const float dtv = dt[(size_t)r * DI + d];
        const float xiv = xi[(size_t)r * DI + d];
        const float B0 = dbl[r * NDBL + 64];
        const float B1 = dbl[r * NDBL + 65];
        const float C0 = dbl[r * NDBL + 66];
        const float C1 = dbl[r * NDBL + 67];
        const float zv = xz[(size_t)r * TWO_DI + DI + d];
        const float dbx = dtv * xiv;
        h0 = fmaf(__expf(dtv * A0), h0, dbx * B0);
        h1 = fmaf(__expf(dtv * A1), h1, dbx * B1);
        const float y = fmaf(h0, C0, fmaf(h1, C1, Dv * xiv));
        yg16[(size_t)r * DI + d] = f2bf(y * siluf(zv));
    }
}

// ---------------------------------------------------------------------------
// LayerNorm over last dim (1024), in-place.
// ---------------------------------------------------------------------------
__global__ __launch_bounds__(256) void ln_kernel(
    float* __restrict__ s,
    const float* __restrict__ g,
    const float* __restrict__ bb)
{
    __shared__ float red[8];
    const size_t base = (size_t)blockIdx.x * DM;
    const int t = threadIdx.x;
    float x0 = s[base + t];
    float x1 = s[base + t + 256];
    float x2 = s[base + t + 512];
    float x3 = s[base + t + 768];
    float sum = x0 + x1 + x2 + x3;
    #pragma unroll
    for (int o = 32; o; o >>= 1) sum += __shfl_down(sum, o, 64);
    const int w = t >> 6, lane = t & 63;
    if (lane == 0) red[w] = sum;
    __syncthreads();
    const float m = (red[0] + red[1] + red[2] + red[3]) * (1.0f / 1024.0f);
    const float d0 = x0 - m, d1 = x1 - m, d2 = x2 - m, d3 = x3 - m;
    float ss = d0 * d0 + d1 * d1 + d2 * d2 + d3 * d3;
    #pragma unroll
    for (int o = 32; o; o >>= 1) ss += __shfl_down(ss, o, 64);
    if (lane == 0) red[4 + w] = ss;
    __syncthreads();
    const float var = (red[4] + red[5] + red[6] + red[7]) * (1.0f / 1024.0f);
    const float inv = rsqrtf(var + 1e-5f);
    s[base + t]       = d0 * inv * g[t]       + bb[t];
    s[base + t + 256] = d1 * inv * g[t + 256] + bb[t + 256];
    s[base + t + 512] = d2 * inv * g[t + 512] + bb[t + 512];
    s[base + t + 768] = d3 * inv * g[t + 768] + bb[t + 768];
}

__global__ __launch_bounds__(256) void final_silu(
    const float* __restrict__ s, float* __restrict__ out)
{
    const size_t i = (size_t)blockIdx.x * 256 + threadIdx.x;
    out[i] = siluf(s[i] + out[i]);
}

// ---------------------------------------------------------------------------
extern "C" void kernel_launch(void* const* d_in, const int* in_sizes, int n_in,
                              void* d_out, int out_size, void* d_ws, size_t ws_size,
                              hipStream_t stream)
{
    const float* x        = (const float*)d_in[0];
    const float* m1_Win   = (const float*)d_in[1];
    const float* m1_convw = (const float*)d_in[2];
    const float* m1_convb = (const float*)d_in[3];
    const float* m1_Wx    = (const float*)d_in[4];
    const float* m1_Wdt   = (const float*)d_in[5];
    const float* m1_bdt   = (const float*)d_in[6];
    const float* m1_Alog  = (const float*)d_in[7];
    const float* m1_D     = (const float*)d_in[8];
    const float* m1_Wout  = (const float*)d_in[9];
    const float* m2_Win   = (const float*)d_in[10];
    const float* m2_convw = (const float*)d_in[11];
    const float* m2_convb = (const float*)d_in[12];
    const float* m2_Wx    = (const float*)d_in[13];
    const float* m2_Wdt   = (const float*)d_in[14];
    const float* m2_bdt   = (const float*)d_in[15];
    const float* m2_Alog  = (const float*)d_in[16];
    const float* m2_D     = (const float*)d_in[17];
    const float* m2_Wout  = (const float*)d_in[18];
    const float* ln1_g    = (const float*)d_in[19];
    const float* ln1_b    = (const float*)d_in[20];
    const float* ln2_g    = (const float*)d_in[21];
    const float* ln2_b    = (const float*)d_in[22];
    const float* W_mid    = (const float*)d_in[23];
    const float* W_spa    = (const float*)d_in[24];
    const float* b_spa    = (const float*)d_in[25];
    const float* W_res    = (const float*)d_in[26];

    float* ws = (float*)d_ws;
    size_t off = 0;
    float* buf_xz  = ws + off; off += (size_t)NROWS * TWO_DI;   // fp32
    float* buf_xi  = ws + off; off += (size_t)NROWS * DI;
    float* buf_dbl = ws + off; off += (size_t)NROWS * NDBL;
    float* buf_dt  = ws + off; off += (size_t)NROWS * DI;       // aliased as residual buf
    float* buf_s   = ws + off; off += (size_t)NROWS * DI;
    // bf16 buffers (as ushort within the float ws)
    unsigned short* bx    = (unsigned short*)(ws + off); off += (size_t)NROWS * DI / 2;
    unsigned short* xi16  = (unsigned short*)(ws + off); off += (size_t)NROWS * DI / 2;
    unsigned short* yg16  = (unsigned short*)(ws + off); off += (size_t)NROWS * DI / 2;
    unsigned short* win16 = (unsigned short*)(ws + off); off += (size_t)TWO_DI * DM / 2;
    unsigned short* wout16= (unsigned short*)(ws + off); off += (size_t)DM * DI / 2;
    unsigned short* wspa16= (unsigned short*)(ws + off); off += (size_t)DM * DM / 2;
    unsigned short* t16   = yg16;   // alias: lifetimes don't overlap (stream-ordered)
    float* buf_res = buf_dt;        // alias: residual path runs after mamba2's scan
    (void)ws_size; (void)n_in; (void)in_sizes; (void)out_size;

    const dim3 blk(256);

    auto mamba = [&](const unsigned short* inp16, const float* Win,
                     const float* convw, const float* convb, const float* Wx,
                     const float* Wdt, const float* bdt, const float* Alog,
                     const float* Dp, const float* Wout, float* out_buf) {
        cast_bf16<<<dim3((TWO_DI * DM) / 1024), blk, 0, stream>>>(Win, win16);
        cast_bf16<<<dim3((DM * DI) / 1024), blk, 0, stream>>>(Wout, wout16);
        // xz = inp @ Win.T : (4096,2048)
        gemm_bf16_nt<0><<<dim3(TWO_DI / 128, NROWS / 128), blk, 0, stream>>>(
            (const short*)inp16, (const short*)win16, nullptr, buf_xz,
            NROWS, TWO_DI, DM);
        // causal depthwise conv + silu
        conv_silu<<<dim3(NROWS), blk, 0, stream>>>(buf_xz, convw, convb, buf_xi, xi16);
        // dbl = xi @ Wx.T : (4096,68)
        gemm_nt<0><<<dim3(2, NROWS / 64), blk, 0, stream>>>(
            buf_xi, DI, Wx, DI, nullptr, buf_dbl, NDBL, NROWS, NDBL, DI);
        // dt = softplus(dbl[:, :64] @ Wdt.T + bdt)
        gemm_nt<1><<<dim3(DI / 64, NROWS / 64), blk, 0, stream>>>(
            buf_dbl, NDBL, Wdt, DTR, bdt, buf_dt, DI, NROWS, DI, DTR);
        // scan -> yg16 (bf16)
        scan_kernel<<<dim3(DI / 256, BATCH), blk, 0, stream>>>(
            buf_dt, buf_xi, buf_xz, buf_dbl, Alog, Dp, yg16);
        // out = yg @ Wout.T : (4096,1024)
        gemm_bf16_nt<0><<<dim3(DM / 128, NROWS / 128), blk, 0, stream>>>(
            (const short*)yg16, (const short*)wout16, nullptr, out_buf,
            NROWS, DM, DI);
    };

    // ---- casts of shared inputs ----
    cast_bf16<<<dim3((NROWS * DM) / 1024), blk, 0, stream>>>(x, bx);
    cast_bf16<<<dim3((DM * DM) / 1024), blk, 0, stream>>>(W_spa, wspa16);

    // ---- Mamba 1 + LN1 ----
    mamba(bx, m1_Win, m1_convw, m1_convb, m1_Wx, m1_Wdt, m1_bdt, m1_Alog, m1_D,
          m1_Wout, buf_s);
    ln_kernel<<<dim3(NROWS), blk, 0, stream>>>(buf_s, ln1_g, ln1_b);

    // ---- channel mix: t16[b] = bf16(silu(W_mid @ buf_s[b])) ----
    gemm_nn_silu<1><<<dim3(DM / 64, LSEQ / 64, BATCH), blk, 0, stream>>>(
        W_mid, buf_s, (void*)t16, LSEQ, DM, LSEQ);

    // ---- Mamba 2 + LN2 ----
    mamba(t16, m2_Win, m2_convw, m2_convb, m2_Wx, m2_Wdt, m2_bdt, m2_Alog,
          m2_D, m2_Wout, buf_s);
    ln_kernel<<<dim3(NROWS), blk, 0, stream>>>(buf_s, ln2_g, ln2_b);

    // ---- residual path: buf_res = silu(x @ W_spa.T + b_spa) ----
    gemm_bf16_nt<2><<<dim3(DM / 128, NROWS / 128), blk, 0, stream>>>(
        (const short*)bx, (const short*)wspa16, b_spa, buf_res,
        NROWS, DM, DM);
    // r2 = silu(W_res @ r) per batch -> d_out
    gemm_nn_silu<0><<<dim3(DM / 64, LSEQ / 64, BATCH), blk, 0, stream>>>(
        W_res, buf_res, d_out, LSEQ, DM, LSEQ);

    // ---- out = silu(s2 + r2) ----
    final_silu<<<dim3((NROWS * DM) / 256), blk, 0, stream>>>(
        buf_s, (float*)d_out);
}

// Round 3
// 630.651 us; speedup vs baseline: 2.3039x; 1.1724x over previous
//
#include <hip/hip_runtime.h>
#include <math.h>

// Problem constants (B=16, L=C=256 scan axis, dm=di=1024, n=2, dtr=64, k=4)
#define BATCH 16
#define LSEQ  256
#define DM    1024
#define DI    1024
#define NROWS (BATCH*LSEQ)   // 4096
#define DTR   64
#define TWO_DI 2048

typedef __attribute__((ext_vector_type(8))) short short8;
typedef __attribute__((ext_vector_type(4))) float floatx4;

__device__ __forceinline__ float siluf(float x) {
    return x / (1.0f + __expf(-x));
}
__device__ __forceinline__ float softplusf(float x) {
    return fmaxf(x, 0.0f) + log1pf(__expf(-fabsf(x)));
}
// fp32 -> bf16 (RNE), raw bits
__device__ __forceinline__ unsigned short f2bf(float f) {
    unsigned int u = __float_as_uint(f);
    u += 0x7fffu + ((u >> 16) & 1u);
    return (unsigned short)(u >> 16);
}
// async global->LDS, 16B per lane; LDS dest = wave-uniform base + lane*16
__device__ __forceinline__ void async16(const short* g, short* l) {
    __builtin_amdgcn_global_load_lds(
        (const __attribute__((address_space(1))) unsigned int*)g,
        (__attribute__((address_space(3))) unsigned int*)l,
        16, 0, 0);
}

// ---------------------------------------------------------------------------
// cast fp32 -> bf16, 4 elts/thread. n multiple of 1024.
// ---------------------------------------------------------------------------
__global__ __launch_bounds__(256) void cast_bf16(
    const float* __restrict__ in, unsigned short* __restrict__ out)
{
    const size_t i = ((size_t)blockIdx.x * 256 + threadIdx.x) * 4;
    const float4 v = *(const float4*)(in + i);
    union { unsigned short s[4]; unsigned long long u; } p;
    p.s[0] = f2bf(v.x); p.s[1] = f2bf(v.y);
    p.s[2] = f2bf(v.z); p.s[3] = f2bf(v.w);
    *(unsigned long long*)(out + i) = p.u;
}

// ---------------------------------------------------------------------------
// bf16 MFMA GEMM (nt): C[M,N] = A[M,K] @ W[N,K]^T, fp32 out.
// A,W bf16 row-major. M%128==0, N%128==0, K%32==0.
// 256 thr = 4 waves in 2x2; 128x128 tile; BK=32; 16x16x32 MFMA, 4x4 per wave.
// EP: 0=none, 1=softplus(v+bias[c]), 2=silu(v+bias[c])
// ---------------------------------------------------------------------------
template <int EP>
__global__ __launch_bounds__(256) void gemm_bf16_nt(
    const short* __restrict__ A,
    const short* __restrict__ W,
    const float* __restrict__ bias,
    float* __restrict__ C,
    int M, int N, int K)
{
    __shared__ short As[128 * 32];   // [m][k], stride 32 elts (64 B)
    __shared__ short Bs[128 * 32];   // [n][k]

    const int tid  = threadIdx.x;
    const int wave = tid >> 6;
    const int lane = tid & 63;
    const int wm = wave >> 1;
    const int wn = wave & 1;
    const int row0 = blockIdx.y * 128;
    const int col0 = blockIdx.x * 128;

    const int srow  = lane >> 2;
    const int skoff = (lane & 3) * 8;
    const short* gA0 = A + (size_t)(row0 + wave * 32 + srow) * K + skoff;
    const short* gA1 = gA0 + (size_t)16 * K;
    const short* gB0 = W + (size_t)(col0 + wave * 32 + srow) * K + skoff;
    const short* gB1 = gB0 + (size_t)16 * K;
    short* lA0 = As + (wave * 32) * 32;
    short* lA1 = lA0 + 16 * 32;
    short* lB0 = Bs + (wave * 32) * 32;
    short* lB1 = lB0 + 16 * 32;

    const int fr = lane & 15;
    const int fk = (lane >> 4) * 8;

    floatx4 acc[4][4] = {};

    for (int k0 = 0; k0 < K; k0 += 32) {
        async16(gA0 + k0, lA0);
        async16(gA1 + k0, lA1);
        async16(gB0 + k0, lB0);
        async16(gB1 + k0, lB1);
        __syncthreads();

        short8 af[4], bfr[4];
        #pragma unroll
        for (int t = 0; t < 4; t++) {
            af[t]  = *(const short8*)&As[(wm * 64 + t * 16 + fr) * 32 + fk];
            bfr[t] = *(const short8*)&Bs[(wn * 64 + t * 16 + fr) * 32 + fk];
        }
        #pragma unroll
        for (int i = 0; i < 4; i++)
            #pragma unroll
            for (int j = 0; j < 4; j++)
                acc[i][j] = __builtin_amdgcn_mfma_f32_16x16x32_bf16(
                    af[i], bfr[j], acc[i][j], 0, 0, 0);
        __syncthreads();
    }

    const int crow = row0 + wm * 64 + (lane >> 4) * 4;
    const int ccol = col0 + wn * 64 + (lane & 15);
    #pragma unroll
    for (int i = 0; i < 4; i++) {
        #pragma unroll
        for (int j = 0; j < 4; j++) {
            const int c = ccol + j * 16;
            float* cp = C + (size_t)(crow + i * 16) * N + c;
            #pragma unroll
            for (int r = 0; r < 4; r++) {
                float v = acc[i][j][r];
                if (EP == 1) v = softplusf(v + bias[c]);
                else if (EP == 2) v = siluf(v + bias[c]);
                cp[(size_t)r * N] = v;
            }
        }
    }
}

// ---------------------------------------------------------------------------
// Batched bf16 MFMA GEMM (nt) + silu: C[b][M,N] = silu(A[M,K] @ W[b][N,K]^T)
// A shared across batch. OUT16: 1 -> bf16 out, 0 -> fp32 out.
// ---------------------------------------------------------------------------
template <int OUT16>
__global__ __launch_bounds__(256) void gemm_bf16_bat(
    const short* __restrict__ A,
    const short* __restrict__ Wb,
    void* __restrict__ Cout,
    int M, int N, int K)
{
    const int bz = blockIdx.z;
    const short* W = Wb + (size_t)bz * N * K;

    __shared__ short As[128 * 32];
    __shared__ short Bs[128 * 32];

    const int tid  = threadIdx.x;
    const int wave = tid >> 6;
    const int lane = tid & 63;
    const int wm = wave >> 1;
    const int wn = wave & 1;
    const int row0 = blockIdx.y * 128;
    const int col0 = blockIdx.x * 128;

    const int srow  = lane >> 2;
    const int skoff = (lane & 3) * 8;
    const short* gA0 = A + (size_t)(row0 + wave * 32 + srow) * K + skoff;
    const short* gA1 = gA0 + (size_t)16 * K;
    const short* gB0 = W + (size_t)(col0 + wave * 32 + srow) * K + skoff;
    const short* gB1 = gB0 + (size_t)16 * K;
    short* lA0 = As + (wave * 32) * 32;
    short* lA1 = lA0 + 16 * 32;
    short* lB0 = Bs + (wave * 32) * 32;
    short* lB1 = lB0 + 16 * 32;

    const int fr = lane & 15;
    const int fk = (lane >> 4) * 8;

    floatx4 acc[4][4] = {};

    for (int k0 = 0; k0 < K; k0 += 32) {
        async16(gA0 + k0, lA0);
        async16(gA1 + k0, lA1);
        async16(gB0 + k0, lB0);
        async16(gB1 + k0, lB1);
        __syncthreads();

        short8 af[4], bfr[4];
        #pragma unroll
        for (int t = 0; t < 4; t++) {
            af[t]  = *(const short8*)&As[(wm * 64 + t * 16 + fr) * 32 + fk];
            bfr[t] = *(const short8*)&Bs[(wn * 64 + t * 16 + fr) * 32 + fk];
        }
        #pragma unroll
        for (int i = 0; i < 4; i++)
            #pragma unroll
            for (int j = 0; j < 4; j++)
                acc[i][j] = __builtin_amdgcn_mfma_f32_16x16x32_bf16(
                    af[i], bfr[j], acc[i][j], 0, 0, 0);
        __syncthreads();
    }

    const int crow = row0 + wm * 64 + (lane >> 4) * 4;
    const int ccol = col0 + wn * 64 + (lane & 15);
    #pragma unroll
    for (int i = 0; i < 4; i++) {
        #pragma unroll
        for (int j = 0; j < 4; j++) {
            const int c = ccol + j * 16;
            #pragma unroll
            for (int r = 0; r < 4; r++) {
                const float v = siluf(acc[i][j][r]);
                const size_t idx = (size_t)bz * M * N + (size_t)(crow + i * 16 + r) * N + c;
                if (OUT16) ((unsigned short*)Cout)[idx] = f2bf(v);
                else       ((float*)Cout)[idx] = v;
            }
        }
    }
}

// ---------------------------------------------------------------------------
// Wcomb = Wdt(1024x64) @ Wx[:64](64x1024), fp32 compute, bf16 out.
// nn GEMM, 64x64 tiles, K=64.
// ---------------------------------------------------------------------------
__global__ __launch_bounds__(256) void gemm_nn_wcomb(
    const float* __restrict__ Wdt,   // (1024, 64)
    const float* __restrict__ Wx,    // (68, 1024) - uses rows 0..63
    unsigned short* __restrict__ C16) // (1024, 1024) bf16
{
    __shared__ float Asf[16][64];
    __shared__ float Bsf[16][64];

    const int tid = threadIdx.x;
    const int tx = tid & 15;
    const int ty = tid >> 4;
    const int row0 = blockIdx.y * 64;
    const int col0 = blockIdx.x * 64;
    const int lrow = tid >> 2;
    const int lcol = (tid & 3) * 4;
    const int bk = tid >> 4;
    const int bn = (tid & 15) * 4;

    float acc[4][4] = {};

    for (int k0 = 0; k0 < 64; k0 += 16) {
        const float4 av = *(const float4*)(Wdt + (size_t)(row0 + lrow) * 64 + k0 + lcol);
        Asf[lcol + 0][lrow] = av.x;
        Asf[lcol + 1][lrow] = av.y;
        Asf[lcol + 2][lrow] = av.z;
        Asf[lcol + 3][lrow] = av.w;
        *(float4*)&Bsf[bk][bn] = *(const float4*)(Wx + (size_t)(k0 + bk) * 1024 + col0 + bn);
        __syncthreads();

        #pragma unroll
        for (int kk = 0; kk < 16; kk++) {
            const float4 a = *(const float4*)&Asf[kk][ty * 4];
            const float4 b = *(const float4*)&Bsf[kk][tx * 4];
            const float af[4] = {a.x, a.y, a.z, a.w};
            const float bfv[4] = {b.x, b.y, b.z, b.w};
            #pragma unroll
            for (int i = 0; i < 4; i++)
                #pragma unroll
                for (int j = 0; j < 4; j++)
                    acc[i][j] = fmaf(af[i], bfv[j], acc[i][j]);
        }
        __syncthreads();
    }

    #pragma unroll
    for (int i = 0; i < 4; i++) {
        const int r = row0 + ty * 4 + i;
        #pragma unroll
        for (int j = 0; j < 4; j++)
            C16[(size_t)r * 1024 + col0 + tx * 4 + j] = f2bf(acc[i][j]);
    }
}

// ---------------------------------------------------------------------------
// Depthwise causal conv (k=4) + bias + SiLU, fused B/C projection.
// Writes fp32 xi, bf16 xi16, and bc[r][0..3] = xi_row . Wx[64+j].
// ---------------------------------------------------------------------------
__global__ __launch_bounds__(256) void conv_silu_bc(
    const float* __restrict__ xz,
    const float* __restrict__ convw,
    const float* __restrict__ convb,
    const float* __restrict__ Wx,     // (68, 1024): rows 64..67 = B0,B1,C0,C1
    float* __restrict__ xi,
    unsigned short* __restrict__ xi16,
    float* __restrict__ bc)           // (4096, 4)
{
    __shared__ float redc[4][4];
    const int r = blockIdx.x;
    const int l = r & (LSEQ - 1);
    const int tid = threadIdx.x;
    float p0 = 0.f, p1 = 0.f, p2 = 0.f, p3 = 0.f;
    #pragma unroll
    for (int i = 0; i < 4; i++) {
        const int d = tid + i * 256;
        const float w0 = convw[d * 4 + 0];
        const float w1 = convw[d * 4 + 1];
        const float w2 = convw[d * 4 + 2];
        const float w3 = convw[d * 4 + 3];
        float acc = w3 * xz[(size_t)r * TWO_DI + d];
        if (l >= 1) acc = fmaf(w2, xz[(size_t)(r - 1) * TWO_DI + d], acc);
        if (l >= 2) acc = fmaf(w1, xz[(size_t)(r - 2) * TWO_DI + d], acc);
        if (l >= 3) acc = fmaf(w0, xz[(size_t)(r - 3) * TWO_DI + d], acc);
        const float v = siluf(acc + convb[d]);
        xi[(size_t)r * DI + d] = v;
        xi16[(size_t)r * DI + d] = f2bf(v);
        p0 = fmaf(v, Wx[64 * 1024 + d], p0);
        p1 = fmaf(v, Wx[65 * 1024 + d], p1);
        p2 = fmaf(v, Wx[66 * 1024 + d], p2);
        p3 = fmaf(v, Wx[67 * 1024 + d], p3);
    }
    #pragma unroll
    for (int o = 32; o; o >>= 1) {
        p0 += __shfl_down(p0, o, 64);
        p1 += __shfl_down(p1, o, 64);
        p2 += __shfl_down(p2, o, 64);
        p3 += __shfl_down(p3, o, 64);
    }
    const int w = tid >> 6, lane = tid & 63;
    if (lane == 0) {
        redc[w][0] = p0; redc[w][1] = p1; redc[w][2] = p2; redc[w][3] = p3;
    }
    __syncthreads();
    if (tid < 4)
        bc[r * 4 + tid] = redc[0][tid] + redc[1][tid] + redc[2][tid] + redc[3][tid];
}

// ---------------------------------------------------------------------------
// Selective scan (n=2), fused D-skip + z-gate, bf16 output.
// ---------------------------------------------------------------------------
__global__ __launch_bounds__(256) void scan_kernel(
    const float* __restrict__ dt,
    const float* __restrict__ xi,
    const float* __restrict__ xz,    // z = cols [1024,2048)
    const float* __restrict__ bc,    // (4096,4): B0,B1,C0,C1
    const float* __restrict__ Alog,
    const float* __restrict__ Dp,
    unsigned short* __restrict__ yg16)
{
    const int d = blockIdx.x * 256 + threadIdx.x;
    const int b = blockIdx.y;
    const float A0 = -__expf(Alog[d * 2 + 0]);
    const float A1 = -__expf(Alog[d * 2 + 1]);
    const float Dv = Dp[d];
    float h0 = 0.f, h1 = 0.f;
    const int rbase = b * LSEQ;
    for (int l = 0; l < LSEQ; l++) {
        const int r = rbase + l;
        const float dtv = dt[(size_t)r * DI + d];
        const float xiv = xi[(size_t)r * DI + d];
        const float4 bcv = *(const float4*)(bc + r * 4);
        const float zv = xz[(size_t)r * TWO_DI + DI + d];
        const float dbx = dtv * xiv;
        h0 = fmaf(__expf(dtv * A0), h0, dbx * bcv.x);
        h1 = fmaf(__expf(dtv * A1), h1, dbx * bcv.y);
        const float y = fmaf(h0, bcv.z, fmaf(h1, bcv.w, Dv * xiv));
        yg16[(size_t)r * DI + d] = f2bf(y * siluf(zv));
    }
}

// ---------------------------------------------------------------------------
// LayerNorm over last dim (1024), in-place.
// ---------------------------------------------------------------------------
__global__ __launch_bounds__(256) void ln_kernel(
    float* __restrict__ s,
    const float* __restrict__ g,
    const float* __restrict__ bb)
{
    __shared__ float red[8];
    const size_t base = (size_t)blockIdx.x * DM;
    const int t = threadIdx.x;
    float x0 = s[base + t];
    float x1 = s[base + t + 256];
    float x2 = s[base + t + 512];
    float x3 = s[base + t + 768];
    float sum = x0 + x1 + x2 + x3;
    #pragma unroll
    for (int o = 32; o; o >>= 1) sum += __shfl_down(sum, o, 64);
    const int w = t >> 6, lane = t & 63;
    if (lane == 0) red[w] = sum;
    __syncthreads();
    const float m = (red[0] + red[1] + red[2] + red[3]) * (1.0f / 1024.0f);
    const float d0 = x0 - m, d1 = x1 - m, d2 = x2 - m, d3 = x3 - m;
    float ss = d0 * d0 + d1 * d1 + d2 * d2 + d3 * d3;
    #pragma unroll
    for (int o = 32; o; o >>= 1) ss += __shfl_down(ss, o, 64);
    if (lane == 0) red[4 + w] = ss;
    __syncthreads();
    const float var = (red[4] + red[5] + red[6] + red[7]) * (1.0f / 1024.0f);
    const float inv = rsqrtf(var + 1e-5f);
    s[base + t]       = d0 * inv * g[t]       + bb[t];
    s[base + t + 256] = d1 * inv * g[t + 256] + bb[t + 256];
    s[base + t + 512] = d2 * inv * g[t + 512] + bb[t + 512];
    s[base + t + 768] = d3 * inv * g[t + 768] + bb[t + 768];
}

// ---------------------------------------------------------------------------
// Per-batch transpose + cast: in fp32 (b, 256 c, 1024 s) -> out bf16 (b, 1024 s, 256 c)
// ---------------------------------------------------------------------------
__global__ __launch_bounds__(256) void transpose_cast(
    const float* __restrict__ in, unsigned short* __restrict__ out)
{
    __shared__ float tile[32][33];
    const int b = blockIdx.z;
    const int c0 = blockIdx.y * 32;
    const int s0 = blockIdx.x * 32;
    const int tx = threadIdx.x & 31;
    const int ty = threadIdx.x >> 5;   // 0..7
    const size_t ib = (size_t)b * 256 * 1024;
    const size_t ob = (size_t)b * 1024 * 256;
    #pragma unroll
    for (int i = 0; i < 4; i++)
        tile[tx][ty + i * 8] = in[ib + (size_t)(c0 + ty + i * 8) * 1024 + s0 + tx];
    __syncthreads();
    #pragma unroll
    for (int i = 0; i < 4; i++)
        out[ob + (size_t)(s0 + ty + i * 8) * 256 + c0 + tx] = f2bf(tile[ty + i * 8][tx]);
}

__global__ __launch_bounds__(256) void final_silu(
    const float* __restrict__ s, float* __restrict__ out)
{
    const size_t i = (size_t)blockIdx.x * 256 + threadIdx.x;
    out[i] = siluf(s[i] + out[i]);
}

// ---------------------------------------------------------------------------
extern "C" void kernel_launch(void* const* d_in, const int* in_sizes, int n_in,
                              void* d_out, int out_size, void* d_ws, size_t ws_size,
                              hipStream_t stream)
{
    const float* x        = (const float*)d_in[0];
    const float* m1_Win   = (const float*)d_in[1];
    const float* m1_convw = (const float*)d_in[2];
    const float* m1_convb = (const float*)d_in[3];
    const float* m1_Wx    = (const float*)d_in[4];
    const float* m1_Wdt   = (const float*)d_in[5];
    const float* m1_bdt   = (const float*)d_in[6];
    const float* m1_Alog  = (const float*)d_in[7];
    const float* m1_D     = (const float*)d_in[8];
    const float* m1_Wout  = (const float*)d_in[9];
    const float* m2_Win   = (const float*)d_in[10];
    const float* m2_convw = (const float*)d_in[11];
    const float* m2_convb = (const float*)d_in[12];
    const float* m2_Wx    = (const float*)d_in[13];
    const float* m2_Wdt   = (const float*)d_in[14];
    const float* m2_bdt   = (const float*)d_in[15];
    const float* m2_Alog  = (const float*)d_in[16];
    const float* m2_D     = (const float*)d_in[17];
    const float* m2_Wout  = (const float*)d_in[18];
    const float* ln1_g    = (const float*)d_in[19];
    const float* ln1_b    = (const float*)d_in[20];
    const float* ln2_g    = (const float*)d_in[21];
    const float* ln2_b    = (const float*)d_in[22];
    const float* W_mid    = (const float*)d_in[23];
    const float* W_spa    = (const float*)d_in[24];
    const float* b_spa    = (const float*)d_in[25];
    const float* W_res    = (const float*)d_in[26];

    float* ws = (float*)d_ws;
    size_t off = 0;
    float* buf_xz  = ws + off; off += (size_t)NROWS * TWO_DI;
    float* buf_xi  = ws + off; off += (size_t)NROWS * DI;
    float* buf_dt  = ws + off; off += (size_t)NROWS * DI;    // aliased: buf_res
    float* buf_s   = ws + off; off += (size_t)NROWS * DI;
    float* buf_bc  = ws + off; off += (size_t)NROWS * 4;
    unsigned short* bx     = (unsigned short*)(ws + off); off += (size_t)NROWS * DI / 2;
    unsigned short* xi16   = (unsigned short*)(ws + off); off += (size_t)NROWS * DI / 2;
    unsigned short* yg16   = (unsigned short*)(ws + off); off += (size_t)NROWS * DI / 2;
    unsigned short* sT16   = (unsigned short*)(ws + off); off += (size_t)NROWS * DI / 2;
    unsigned short* win16  = (unsigned short*)(ws + off); off += (size_t)TWO_DI * DM / 2;
    unsigned short* wout16 = (unsigned short*)(ws + off); off += (size_t)DM * DI / 2;
    unsigned short* wspa16 = (unsigned short*)(ws + off); off += (size_t)DM * DM / 2;
    unsigned short* wcomb16= (unsigned short*)(ws + off); off += (size_t)DI * DI / 2;
    unsigned short* wmid16 = (unsigned short*)(ws + off); off += (size_t)LSEQ * LSEQ / 2;
    unsigned short* wres16 = (unsigned short*)(ws + off); off += (size_t)LSEQ * LSEQ / 2;
    unsigned short* t16 = yg16;    // mid-mix out / mamba2 in (lifetimes disjoint)
    float* buf_res = buf_dt;       // residual path after mamba2 scan done
    unsigned short* rT16 = sT16;   // residual transpose after mid-mix done
    (void)ws_size; (void)n_in; (void)in_sizes; (void)out_size;

    const dim3 blk(256);

    auto mamba = [&](const unsigned short* inp16, const float* Win,
                     const float* convw, const float* convb, const float* Wx,
                     const float* Wdt, const float* bdt, const float* Alog,
                     const float* Dp, const float* Wout, float* out_buf) {
        cast_bf16<<<dim3((TWO_DI * DM) / 1024), blk, 0, stream>>>(Win, win16);
        cast_bf16<<<dim3((DM * DI) / 1024), blk, 0, stream>>>(Wout, wout16);
        // Wcomb = Wdt @ Wx[:64]  (1024,1024) bf16
        gemm_nn_wcomb<<<dim3(16, 16), blk, 0, stream>>>(Wdt, Wx, wcomb16);
        // xz = inp @ Win.T : (4096,2048)
        gemm_bf16_nt<0><<<dim3(TWO_DI / 128, NROWS / 128), blk, 0, stream>>>(
            (const short*)inp16, (const short*)win16, nullptr, buf_xz,
            NROWS, TWO_DI, DM);
        // conv + silu + fused B/C projection
        conv_silu_bc<<<dim3(NROWS), blk, 0, stream>>>(
            buf_xz, convw, convb, Wx, buf_xi, xi16, buf_bc);
        // dt = softplus(xi @ Wcomb.T + bdt) : (4096,1024) via MFMA
        gemm_bf16_nt<1><<<dim3(DI / 128, NROWS / 128), blk, 0, stream>>>(
            (const short*)xi16, (const short*)wcomb16, bdt, buf_dt,
            NROWS, DI, DI);
        // scan -> yg16 (bf16)
        scan_kernel<<<dim3(DI / 256, BATCH), blk, 0, stream>>>(
            buf_dt, buf_xi, buf_xz, buf_bc, Alog, Dp, yg16);
        // out = yg @ Wout.T : (4096,1024)
        gemm_bf16_nt<0><<<dim3(DM / 128, NROWS / 128), blk, 0, stream>>>(
            (const short*)yg16, (const short*)wout16, nullptr, out_buf,
            NROWS, DM, DI);
    };

    // ---- casts of shared inputs ----
    cast_bf16<<<dim3((NROWS * DM) / 1024), blk, 0, stream>>>(x, bx);
    cast_bf16<<<dim3((DM * DM) / 1024), blk, 0, stream>>>(W_spa, wspa16);
    cast_bf16<<<dim3((LSEQ * LSEQ) / 1024), blk, 0, stream>>>(W_mid, wmid16);
    cast_bf16<<<dim3((LSEQ * LSEQ) / 1024), blk, 0, stream>>>(W_res, wres16);

    // ---- Mamba 1 + LN1 ----
    mamba(bx, m1_Win, m1_convw, m1_convb, m1_Wx, m1_Wdt, m1_bdt, m1_Alog, m1_D,
          m1_Wout, buf_s);
    ln_kernel<<<dim3(NROWS), blk, 0, stream>>>(buf_s, ln1_g, ln1_b);

    // ---- channel mix 1: t16[b] = bf16(silu(W_mid @ s[b])) via MFMA ----
    transpose_cast<<<dim3(32, 8, BATCH), blk, 0, stream>>>(buf_s, sT16);
    gemm_bf16_bat<1><<<dim3(DM / 128, LSEQ / 128, BATCH), blk, 0, stream>>>(
        (const short*)wmid16, (const short*)sT16, (void*)t16, LSEQ, DM, LSEQ);

    // ---- Mamba 2 + LN2 ----
    mamba(t16, m2_Win, m2_convw, m2_convb, m2_Wx, m2_Wdt, m2_bdt, m2_Alog,
          m2_D, m2_Wout, buf_s);
    ln_kernel<<<dim3(NROWS), blk, 0, stream>>>(buf_s, ln2_g, ln2_b);

    // ---- residual path: buf_res = silu(x @ W_spa.T + b_spa) ----
    gemm_bf16_nt<2><<<dim3(DM / 128, NROWS / 128), blk, 0, stream>>>(
        (const short*)bx, (const short*)wspa16, b_spa, buf_res,
        NROWS, DM, DM);
    // channel mix 2: d_out[b] = silu(W_res @ r[b]) via MFMA
    transpose_cast<<<dim3(32, 8, BATCH), blk, 0, stream>>>(buf_res, rT16);
    gemm_bf16_bat<0><<<dim3(DM / 128, LSEQ / 128, BATCH), blk, 0, stream>>>(
        (const short*)wres16, (const short*)rT16, d_out, LSEQ, DM, LSEQ);

    // ---- out = silu(s2 + r2) ----
    final_silu<<<dim3((NROWS * DM) / 256), blk, 0, stream>>>(
        buf_s, (float*)d_out);
}

// Round 4
// 531.807 us; speedup vs baseline: 2.7321x; 1.1859x over previous
//
#include <hip/hip_runtime.h>
#include <math.h>

// Problem constants (B=16, L=C=256 scan axis, dm=di=1024, n=2, dtr=64, k=4)
#define BATCH 16
#define LSEQ  256
#define DM    1024
#define DI    1024
#define NROWS (BATCH*LSEQ)   // 4096
#define DTR   64
#define TWO_DI 2048
#define NCH   16             // scan chunks
#define CHL   16             // chunk length (NCH*CHL == LSEQ)

typedef __attribute__((ext_vector_type(8))) short short8;
typedef __attribute__((ext_vector_type(4))) float floatx4;

__device__ __forceinline__ float siluf(float x) {
    return x / (1.0f + __expf(-x));
}
__device__ __forceinline__ float softplusf(float x) {
    return fmaxf(x, 0.0f) + log1pf(__expf(-fabsf(x)));
}
// fp32 -> bf16 (RNE), raw bits
__device__ __forceinline__ unsigned short f2bf(float f) {
    unsigned int u = __float_as_uint(f);
    u += 0x7fffu + ((u >> 16) & 1u);
    return (unsigned short)(u >> 16);
}
__device__ __forceinline__ float bf2f(unsigned short s) {
    return __uint_as_float(((unsigned int)s) << 16);
}
// async global->LDS, 16B per lane; LDS dest = wave-uniform base + lane*16
__device__ __forceinline__ void async16(const short* g, short* l) {
    __builtin_amdgcn_global_load_lds(
        (const __attribute__((address_space(1))) unsigned int*)g,
        (__attribute__((address_space(3))) unsigned int*)l,
        16, 0, 0);
}

// ---------------------------------------------------------------------------
// cast fp32 -> bf16, 4 elts/thread. n multiple of 1024.
// ---------------------------------------------------------------------------
__global__ __launch_bounds__(256) void cast_bf16(
    const float* __restrict__ in, unsigned short* __restrict__ out)
{
    const size_t i = ((size_t)blockIdx.x * 256 + threadIdx.x) * 4;
    const float4 v = *(const float4*)(in + i);
    union { unsigned short s[4]; unsigned long long u; } p;
    p.s[0] = f2bf(v.x); p.s[1] = f2bf(v.y);
    p.s[2] = f2bf(v.z); p.s[3] = f2bf(v.w);
    *(unsigned long long*)(out + i) = p.u;
}

// ---------------------------------------------------------------------------
// bf16 MFMA GEMM (nt): C[M,N] = A[M,K] @ W[N,K]^T.
// A,W bf16 row-major. M%128==0, N%128==0, K%32==0.
// 256 thr = 4 waves in 2x2; 128x128 tile; BK=32; 16x16x32 MFMA, 4x4 per wave.
// EP: 0=none, 1=softplus(v+bias[c]), 2=silu(v+bias[c])
// OUT16: 1 -> bf16 out, 0 -> fp32 out
// ---------------------------------------------------------------------------
template <int EP, int OUT16>
__global__ __launch_bounds__(256) void gemm_bf16_nt(
    const short* __restrict__ A,
    const short* __restrict__ W,
    const float* __restrict__ bias,
    void* __restrict__ Cout,
    int M, int N, int K)
{
    __shared__ short As[128 * 32];   // [m][k], stride 32 elts (64 B)
    __shared__ short Bs[128 * 32];   // [n][k]

    const int tid  = threadIdx.x;
    const int wave = tid >> 6;
    const int lane = tid & 63;
    const int wm = wave >> 1;
    const int wn = wave & 1;
    const int row0 = blockIdx.y * 128;
    const int col0 = blockIdx.x * 128;

    const int srow  = lane >> 2;
    const int skoff = (lane & 3) * 8;
    const short* gA0 = A + (size_t)(row0 + wave * 32 + srow) * K + skoff;
    const short* gA1 = gA0 + (size_t)16 * K;
    const short* gB0 = W + (size_t)(col0 + wave * 32 + srow) * K + skoff;
    const short* gB1 = gB0 + (size_t)16 * K;
    short* lA0 = As + (wave * 32) * 32;
    short* lA1 = lA0 + 16 * 32;
    short* lB0 = Bs + (wave * 32) * 32;
    short* lB1 = lB0 + 16 * 32;

    const int fr = lane & 15;
    const int fk = (lane >> 4) * 8;

    floatx4 acc[4][4] = {};

    for (int k0 = 0; k0 < K; k0 += 32) {
        async16(gA0 + k0, lA0);
        async16(gA1 + k0, lA1);
        async16(gB0 + k0, lB0);
        async16(gB1 + k0, lB1);
        __syncthreads();

        short8 af[4], bfr[4];
        #pragma unroll
        for (int t = 0; t < 4; t++) {
            af[t]  = *(const short8*)&As[(wm * 64 + t * 16 + fr) * 32 + fk];
            bfr[t] = *(const short8*)&Bs[(wn * 64 + t * 16 + fr) * 32 + fk];
        }
        #pragma unroll
        for (int i = 0; i < 4; i++)
            #pragma unroll
            for (int j = 0; j < 4; j++)
                acc[i][j] = __builtin_amdgcn_mfma_f32_16x16x32_bf16(
                    af[i], bfr[j], acc[i][j], 0, 0, 0);
        __syncthreads();
    }

    const int crow = row0 + wm * 64 + (lane >> 4) * 4;
    const int ccol = col0 + wn * 64 + (lane & 15);
    #pragma unroll
    for (int i = 0; i < 4; i++) {
        #pragma unroll
        for (int j = 0; j < 4; j++) {
            const int c = ccol + j * 16;
            #pragma unroll
            for (int r = 0; r < 4; r++) {
                float v = acc[i][j][r];
                if (EP == 1) v = softplusf(v + bias[c]);
                else if (EP == 2) v = siluf(v + bias[c]);
                const size_t idx = (size_t)(crow + i * 16 + r) * N + c;
                if (OUT16) ((unsigned short*)Cout)[idx] = f2bf(v);
                else       ((float*)Cout)[idx] = v;
            }
        }
    }
}

// ---------------------------------------------------------------------------
// Batched bf16 MFMA GEMM (nt) + silu: C[b][M,N] = silu(A[M,K] @ W[b][N,K]^T)
// A shared across batch. OUT16: 1 -> bf16 out, 0 -> fp32 out.
// ---------------------------------------------------------------------------
template <int OUT16>
__global__ __launch_bounds__(256) void gemm_bf16_bat(
    const short* __restrict__ A,
    const short* __restrict__ Wb,
    void* __restrict__ Cout,
    int M, int N, int K)
{
    const int bz = blockIdx.z;
    const short* W = Wb + (size_t)bz * N * K;

    __shared__ short As[128 * 32];
    __shared__ short Bs[128 * 32];

    const int tid  = threadIdx.x;
    const int wave = tid >> 6;
    const int lane = tid & 63;
    const int wm = wave >> 1;
    const int wn = wave & 1;
    const int row0 = blockIdx.y * 128;
    const int col0 = blockIdx.x * 128;

    const int srow  = lane >> 2;
    const int skoff = (lane & 3) * 8;
    const short* gA0 = A + (size_t)(row0 + wave * 32 + srow) * K + skoff;
    const short* gA1 = gA0 + (size_t)16 * K;
    const short* gB0 = W + (size_t)(col0 + wave * 32 + srow) * K + skoff;
    const short* gB1 = gB0 + (size_t)16 * K;
    short* lA0 = As + (wave * 32) * 32;
    short* lA1 = lA0 + 16 * 32;
    short* lB0 = Bs + (wave * 32) * 32;
    short* lB1 = lB0 + 16 * 32;

    const int fr = lane & 15;
    const int fk = (lane >> 4) * 8;

    floatx4 acc[4][4] = {};

    for (int k0 = 0; k0 < K; k0 += 32) {
        async16(gA0 + k0, lA0);
        async16(gA1 + k0, lA1);
        async16(gB0 + k0, lB0);
        async16(gB1 + k0, lB1);
        __syncthreads();

        short8 af[4], bfr[4];
        #pragma unroll
        for (int t = 0; t < 4; t++) {
            af[t]  = *(const short8*)&As[(wm * 64 + t * 16 + fr) * 32 + fk];
            bfr[t] = *(const short8*)&Bs[(wn * 64 + t * 16 + fr) * 32 + fk];
        }
        #pragma unroll
        for (int i = 0; i < 4; i++)
            #pragma unroll
            for (int j = 0; j < 4; j++)
                acc[i][j] = __builtin_amdgcn_mfma_f32_16x16x32_bf16(
                    af[i], bfr[j], acc[i][j], 0, 0, 0);
        __syncthreads();
    }

    const int crow = row0 + wm * 64 + (lane >> 4) * 4;
    const int ccol = col0 + wn * 64 + (lane & 15);
    #pragma unroll
    for (int i = 0; i < 4; i++) {
        #pragma unroll
        for (int j = 0; j < 4; j++) {
            const int c = ccol + j * 16;
            #pragma unroll
            for (int r = 0; r < 4; r++) {
                const float v = siluf(acc[i][j][r]);
                const size_t idx = (size_t)bz * M * N + (size_t)(crow + i * 16 + r) * N + c;
                if (OUT16) ((unsigned short*)Cout)[idx] = f2bf(v);
                else       ((float*)Cout)[idx] = v;
            }
        }
    }
}

// ---------------------------------------------------------------------------
// Wcomb = Wdt(1024x64) @ Wx[:64](64x1024), fp32 compute, bf16 out.
// ---------------------------------------------------------------------------
__global__ __launch_bounds__(256) void gemm_nn_wcomb(
    const float* __restrict__ Wdt,   // (1024, 64)
    const float* __restrict__ Wx,    // (68, 1024) - uses rows 0..63
    unsigned short* __restrict__ C16) // (1024, 1024) bf16
{
    __shared__ float Asf[16][64];
    __shared__ float Bsf[16][64];

    const int tid = threadIdx.x;
    const int tx = tid & 15;
    const int ty = tid >> 4;
    const int row0 = blockIdx.y * 64;
    const int col0 = blockIdx.x * 64;
    const int lrow = tid >> 2;
    const int lcol = (tid & 3) * 4;
    const int bk = tid >> 4;
    const int bn = (tid & 15) * 4;

    float acc[4][4] = {};

    for (int k0 = 0; k0 < 64; k0 += 16) {
        const float4 av = *(const float4*)(Wdt + (size_t)(row0 + lrow) * 64 + k0 + lcol);
        Asf[lcol + 0][lrow] = av.x;
        Asf[lcol + 1][lrow] = av.y;
        Asf[lcol + 2][lrow] = av.z;
        Asf[lcol + 3][lrow] = av.w;
        *(float4*)&Bsf[bk][bn] = *(const float4*)(Wx + (size_t)(k0 + bk) * 1024 + col0 + bn);
        __syncthreads();

        #pragma unroll
        for (int kk = 0; kk < 16; kk++) {
            const float4 a = *(const float4*)&Asf[kk][ty * 4];
            const float4 b = *(const float4*)&Bsf[kk][tx * 4];
            const float af[4] = {a.x, a.y, a.z, a.w};
            const float bfv[4] = {b.x, b.y, b.z, b.w};
            #pragma unroll
            for (int i = 0; i < 4; i++)
                #pragma unroll
                for (int j = 0; j < 4; j++)
                    acc[i][j] = fmaf(af[i], bfv[j], acc[i][j]);
        }
        __syncthreads();
    }

    #pragma unroll
    for (int i = 0; i < 4; i++) {
        const int r = row0 + ty * 4 + i;
        #pragma unroll
        for (int j = 0; j < 4; j++)
            C16[(size_t)r * 1024 + col0 + tx * 4 + j] = f2bf(acc[i][j]);
    }
}

// ---------------------------------------------------------------------------
// Depthwise causal conv (k=4) + bias + SiLU, fused B/C projection.
// Writes bf16 xi16 and bc[r][0..3] = xi_row . Wx[64+j].
// ---------------------------------------------------------------------------
__global__ __launch_bounds__(256) void conv_silu_bc(
    const float* __restrict__ xz,
    const float* __restrict__ convw,
    const float* __restrict__ convb,
    const float* __restrict__ Wx,     // (68, 1024): rows 64..67 = B0,B1,C0,C1
    unsigned short* __restrict__ xi16,
    float* __restrict__ bc)           // (4096, 4)
{
    __shared__ float redc[4][4];
    const int r = blockIdx.x;
    const int l = r & (LSEQ - 1);
    const int tid = threadIdx.x;
    float p0 = 0.f, p1 = 0.f, p2 = 0.f, p3 = 0.f;
    #pragma unroll
    for (int i = 0; i < 4; i++) {
        const int d = tid + i * 256;
        const float w0 = convw[d * 4 + 0];
        const float w1 = convw[d * 4 + 1];
        const float w2 = convw[d * 4 + 2];
        const float w3 = convw[d * 4 + 3];
        float acc = w3 * xz[(size_t)r * TWO_DI + d];
        if (l >= 1) acc = fmaf(w2, xz[(size_t)(r - 1) * TWO_DI + d], acc);
        if (l >= 2) acc = fmaf(w1, xz[(size_t)(r - 2) * TWO_DI + d], acc);
        if (l >= 3) acc = fmaf(w0, xz[(size_t)(r - 3) * TWO_DI + d], acc);
        const float v = siluf(acc + convb[d]);
        xi16[(size_t)r * DI + d] = f2bf(v);
        p0 = fmaf(v, Wx[64 * 1024 + d], p0);
        p1 = fmaf(v, Wx[65 * 1024 + d], p1);
        p2 = fmaf(v, Wx[66 * 1024 + d], p2);
        p3 = fmaf(v, Wx[67 * 1024 + d], p3);
    }
    #pragma unroll
    for (int o = 32; o; o >>= 1) {
        p0 += __shfl_down(p0, o, 64);
        p1 += __shfl_down(p1, o, 64);
        p2 += __shfl_down(p2, o, 64);
        p3 += __shfl_down(p3, o, 64);
    }
    const int w = tid >> 6, lane = tid & 63;
    if (lane == 0) {
        redc[w][0] = p0; redc[w][1] = p1; redc[w][2] = p2; redc[w][3] = p3;
    }
    __syncthreads();
    if (tid < 4)
        bc[r * 4 + tid] = redc[0][tid] + redc[1][tid] + redc[2][tid] + redc[3][tid];
}

// ---------------------------------------------------------------------------
// Chunked selective scan (n=2). NCH chunks of CHL steps.
// part1: per-chunk local end-state (h0,h1) and decay product (p0,p1), h(0)=0.
// ---------------------------------------------------------------------------
__global__ __launch_bounds__(256) void scan_part1(
    const unsigned short* __restrict__ dt16,
    const unsigned short* __restrict__ xi16,
    const float* __restrict__ bc,
    const float* __restrict__ Alog,
    float4* __restrict__ hc)          // (B, NCH, DI)
{
    const int d  = blockIdx.x * 256 + threadIdx.x;
    const int b  = blockIdx.y;
    const int ch = blockIdx.z;
    const float A0 = -__expf(Alog[d * 2 + 0]);
    const float A1 = -__expf(Alog[d * 2 + 1]);
    float h0 = 0.f, h1 = 0.f, p0 = 1.f, p1 = 1.f;
    const int r0 = b * LSEQ + ch * CHL;
    #pragma unroll 4
    for (int l = 0; l < CHL; l++) {
        const int r = r0 + l;
        const float dtv = bf2f(dt16[(size_t)r * DI + d]);
        const float xiv = bf2f(xi16[(size_t)r * DI + d]);
        const float4 bcv = *(const float4*)(bc + r * 4);
        const float e0 = __expf(dtv * A0);
        const float e1 = __expf(dtv * A1);
        const float dbx = dtv * xiv;
        h0 = fmaf(e0, h0, dbx * bcv.x);
        h1 = fmaf(e1, h1, dbx * bcv.y);
        p0 *= e0; p1 *= e1;
    }
    hc[(size_t)(b * NCH + ch) * DI + d] = make_float4(h0, h1, p0, p1);
}

// carry: sequential over chunks; writes carry-in state per chunk.
__global__ __launch_bounds__(256) void scan_carry(
    const float4* __restrict__ hc,
    float2* __restrict__ ci)          // (B, NCH, DI)
{
    const int d = blockIdx.x * 256 + threadIdx.x;
    const int b = blockIdx.y;
    float c0 = 0.f, c1 = 0.f;
    #pragma unroll
    for (int ch = 0; ch < NCH; ch++) {
        const size_t idx = (size_t)(b * NCH + ch) * DI + d;
        const float4 v = hc[idx];
        ci[idx] = make_float2(c0, c1);
        c0 = fmaf(v.z, c0, v.x);
        c1 = fmaf(v.w, c1, v.y);
    }
}

// part2: redo chunk recurrence seeded with carry; fused C-proj + D-skip + z-gate.
__global__ __launch_bounds__(256) void scan_part2(
    const unsigned short* __restrict__ dt16,
    const unsigned short* __restrict__ xi16,
    const float* __restrict__ xz,     // z = cols [1024,2048)
    const float* __restrict__ bc,
    const float* __restrict__ Alog,
    const float* __restrict__ Dp,
    const float2* __restrict__ ci,
    unsigned short* __restrict__ yg16)
{
    const int d  = blockIdx.x * 256 + threadIdx.x;
    const int b  = blockIdx.y;
    const int ch = blockIdx.z;
    const float A0 = -__expf(Alog[d * 2 + 0]);
    const float A1 = -__expf(Alog[d * 2 + 1]);
    const float Dv = Dp[d];
    const float2 c = ci[(size_t)(b * NCH + ch) * DI + d];
    float h0 = c.x, h1 = c.y;
    const int r0 = b * LSEQ + ch * CHL;
    #pragma unroll 4
    for (int l = 0; l < CHL; l++) {
        const int r = r0 + l;
        const float dtv = bf2f(dt16[(size_t)r * DI + d]);
        const float xiv = bf2f(xi16[(size_t)r * DI + d]);
        const float4 bcv = *(const float4*)(bc + r * 4);
        const float zv = xz[(size_t)r * TWO_DI + DI + d];
        const float e0 = __expf(dtv * A0);
        const float e1 = __expf(dtv * A1);
        const float dbx = dtv * xiv;
        h0 = fmaf(e0, h0, dbx * bcv.x);
        h1 = fmaf(e1, h1, dbx * bcv.y);
        const float y = fmaf(h0, bcv.z, fmaf(h1, bcv.w, Dv * xiv));
        yg16[(size_t)r * DI + d] = f2bf(y * siluf(zv));
    }
}

// ---------------------------------------------------------------------------
// LayerNorm over last dim (1024), in-place.
// ---------------------------------------------------------------------------
__global__ __launch_bounds__(256) void ln_kernel(
    float* __restrict__ s,
    const float* __restrict__ g,
    const float* __restrict__ bb)
{
    __shared__ float red[8];
    const size_t base = (size_t)blockIdx.x * DM;
    const int t = threadIdx.x;
    float x0 = s[base + t];
    float x1 = s[base + t + 256];
    float x2 = s[base + t + 512];
    float x3 = s[base + t + 768];
    float sum = x0 + x1 + x2 + x3;
    #pragma unroll
    for (int o = 32; o; o >>= 1) sum += __shfl_down(sum, o, 64);
    const int w = t >> 6, lane = t & 63;
    if (lane == 0) red[w] = sum;
    __syncthreads();
    const float m = (red[0] + red[1] + red[2] + red[3]) * (1.0f / 1024.0f);
    const float d0 = x0 - m, d1 = x1 - m, d2 = x2 - m, d3 = x3 - m;
    float ss = d0 * d0 + d1 * d1 + d2 * d2 + d3 * d3;
    #pragma unroll
    for (int o = 32; o; o >>= 1) ss += __shfl_down(ss, o, 64);
    if (lane == 0) red[4 + w] = ss;
    __syncthreads();
    const float var = (red[4] + red[5] + red[6] + red[7]) * (1.0f / 1024.0f);
    const float inv = rsqrtf(var + 1e-5f);
    s[base + t]       = d0 * inv * g[t]       + bb[t];
    s[base + t + 256] = d1 * inv * g[t + 256] + bb[t + 256];
    s[base + t + 512] = d2 * inv * g[t + 512] + bb[t + 512];
    s[base + t + 768] = d3 * inv * g[t + 768] + bb[t + 768];
}

// ---------------------------------------------------------------------------
// Per-batch transpose + cast: fp32 (b, 256 c, 1024 s) -> bf16 (b, 1024 s, 256 c)
// ---------------------------------------------------------------------------
__global__ __launch_bounds__(256) void transpose_cast(
    const float* __restrict__ in, unsigned short* __restrict__ out)
{
    __shared__ float tile[32][33];
    const int b = blockIdx.z;
    const int c0 = blockIdx.y * 32;
    const int s0 = blockIdx.x * 32;
    const int tx = threadIdx.x & 31;
    const int ty = threadIdx.x >> 5;   // 0..7
    const size_t ib = (size_t)b * 256 * 1024;
    const size_t ob = (size_t)b * 1024 * 256;
    #pragma unroll
    for (int i = 0; i < 4; i++)
        tile[tx][ty + i * 8] = in[ib + (size_t)(c0 + ty + i * 8) * 1024 + s0 + tx];
    __syncthreads();
    #pragma unroll
    for (int i = 0; i < 4; i++)
        out[ob + (size_t)(s0 + ty + i * 8) * 256 + c0 + tx] = f2bf(tile[ty + i * 8][tx]);
}

__global__ __launch_bounds__(256) void final_silu(
    const float* __restrict__ s, float* __restrict__ out)
{
    const size_t i = (size_t)blockIdx.x * 256 + threadIdx.x;
    out[i] = siluf(s[i] + out[i]);
}

// ---------------------------------------------------------------------------
extern "C" void kernel_launch(void* const* d_in, const int* in_sizes, int n_in,
                              void* d_out, int out_size, void* d_ws, size_t ws_size,
                              hipStream_t stream)
{
    const float* x        = (const float*)d_in[0];
    const float* m1_Win   = (const float*)d_in[1];
    const float* m1_convw = (const float*)d_in[2];
    const float* m1_convb = (const float*)d_in[3];
    const float* m1_Wx    = (const float*)d_in[4];
    const float* m1_Wdt   = (const float*)d_in[5];
    const float* m1_bdt   = (const float*)d_in[6];
    const float* m1_Alog  = (const float*)d_in[7];
    const float* m1_D     = (const float*)d_in[8];
    const float* m1_Wout  = (const float*)d_in[9];
    const float* m2_Win   = (const float*)d_in[10];
    const float* m2_convw = (const float*)d_in[11];
    const float* m2_convb = (const float*)d_in[12];
    const float* m2_Wx    = (const float*)d_in[13];
    const float* m2_Wdt   = (const float*)d_in[14];
    const float* m2_bdt   = (const float*)d_in[15];
    const float* m2_Alog  = (const float*)d_in[16];
    const float* m2_D     = (const float*)d_in[17];
    const float* m2_Wout  = (const float*)d_in[18];
    const float* ln1_g    = (const float*)d_in[19];
    const float* ln1_b    = (const float*)d_in[20];
    const float* ln2_g    = (const float*)d_in[21];
    const float* ln2_b    = (const float*)d_in[22];
    const float* W_mid    = (const float*)d_in[23];
    const float* W_spa    = (const float*)d_in[24];
    const float* b_spa    = (const float*)d_in[25];
    const float* W_res    = (const float*)d_in[26];

    float* ws = (float*)d_ws;
    size_t off = 0;
    float* buf_xz  = ws + off; off += (size_t)NROWS * TWO_DI;          // 32 MB
    float* buf_s   = ws + off; off += (size_t)NROWS * DI;              // 16 MB
    float* buf_bc  = ws + off; off += (size_t)NROWS * 4;
    float4* buf_hc = (float4*)(ws + off); off += (size_t)BATCH * NCH * DI * 4;  // 4 MB
    float2* buf_ci = (float2*)(ws + off); off += (size_t)BATCH * NCH * DI * 2;  // 2 MB
    unsigned short* bx     = (unsigned short*)(ws + off); off += (size_t)NROWS * DI / 2;
    unsigned short* xi16   = (unsigned short*)(ws + off); off += (size_t)NROWS * DI / 2;
    unsigned short* yg16   = (unsigned short*)(ws + off); off += (size_t)NROWS * DI / 2;
    unsigned short* sT16   = (unsigned short*)(ws + off); off += (size_t)NROWS * DI / 2;
    unsigned short* dt16   = (unsigned short*)(ws + off); off += (size_t)NROWS * DI / 2;
    unsigned short* win16  = (unsigned short*)(ws + off); off += (size_t)TWO_DI * DM / 2;
    unsigned short* wout16 = (unsigned short*)(ws + off); off += (size_t)DM * DI / 2;
    unsigned short* wspa16 = (unsigned short*)(ws + off); off += (size_t)DM * DM / 2;
    unsigned short* wcomb16= (unsigned short*)(ws + off); off += (size_t)DI * DI / 2;
    unsigned short* wmid16 = (unsigned short*)(ws + off); off += (size_t)LSEQ * LSEQ / 2;
    unsigned short* wres16 = (unsigned short*)(ws + off); off += (size_t)LSEQ * LSEQ / 2;
    unsigned short* t16 = yg16;    // mid-mix out / mamba2 in (lifetimes disjoint)
    float* buf_res = buf_xz;       // residual path after mamba2's scans done with xz
    unsigned short* rT16 = sT16;   // residual transpose after mid-mix done
    (void)ws_size; (void)n_in; (void)in_sizes; (void)out_size;

    const dim3 blk(256);

    auto mamba = [&](const unsigned short* inp16, const float* Win,
                     const float* convw, const float* convb, const float* Wx,
                     const float* Wdt, const float* bdt, const float* Alog,
                     const float* Dp, const float* Wout, float* out_buf) {
        cast_bf16<<<dim3((TWO_DI * DM) / 1024), blk, 0, stream>>>(Win, win16);
        cast_bf16<<<dim3((DM * DI) / 1024), blk, 0, stream>>>(Wout, wout16);
        // Wcomb = Wdt @ Wx[:64]  (1024,1024) bf16
        gemm_nn_wcomb<<<dim3(16, 16), blk, 0, stream>>>(Wdt, Wx, wcomb16);
        // xz = inp @ Win.T : (4096,2048)
        gemm_bf16_nt<0, 0><<<dim3(TWO_DI / 128, NROWS / 128), blk, 0, stream>>>(
            (const short*)inp16, (const short*)win16, nullptr, buf_xz,
            NROWS, TWO_DI, DM);
        // conv + silu + fused B/C projection -> xi16, bc
        conv_silu_bc<<<dim3(NROWS), blk, 0, stream>>>(
            buf_xz, convw, convb, Wx, xi16, buf_bc);
        // dt16 = bf16(softplus(xi @ Wcomb.T + bdt))
        gemm_bf16_nt<1, 1><<<dim3(DI / 128, NROWS / 128), blk, 0, stream>>>(
            (const short*)xi16, (const short*)wcomb16, bdt, dt16,
            NROWS, DI, DI);
        // chunked scan -> yg16
        scan_part1<<<dim3(DI / 256, BATCH, NCH), blk, 0, stream>>>(
            dt16, xi16, buf_bc, Alog, buf_hc);
        scan_carry<<<dim3(DI / 256, BATCH), blk, 0, stream>>>(buf_hc, buf_ci);
        scan_part2<<<dim3(DI / 256, BATCH, NCH), blk, 0, stream>>>(
            dt16, xi16, buf_xz, buf_bc, Alog, Dp, buf_ci, yg16);
        // out = yg @ Wout.T : (4096,1024)
        gemm_bf16_nt<0, 0><<<dim3(DM / 128, NROWS / 128), blk, 0, stream>>>(
            (const short*)yg16, (const short*)wout16, nullptr, out_buf,
            NROWS, DM, DI);
    };

    // ---- casts of shared inputs ----
    cast_bf16<<<dim3((NROWS * DM) / 1024), blk, 0, stream>>>(x, bx);
    cast_bf16<<<dim3((DM * DM) / 1024), blk, 0, stream>>>(W_spa, wspa16);
    cast_bf16<<<dim3((LSEQ * LSEQ) / 1024), blk, 0, stream>>>(W_mid, wmid16);
    cast_bf16<<<dim3((LSEQ * LSEQ) / 1024), blk, 0, stream>>>(W_res, wres16);

    // ---- Mamba 1 + LN1 ----
    mamba(bx, m1_Win, m1_convw, m1_convb, m1_Wx, m1_Wdt, m1_bdt, m1_Alog, m1_D,
          m1_Wout, buf_s);
    ln_kernel<<<dim3(NROWS), blk, 0, stream>>>(buf_s, ln1_g, ln1_b);

    // ---- channel mix 1: t16[b] = bf16(silu(W_mid @ s[b])) via MFMA ----
    transpose_cast<<<dim3(32, 8, BATCH), blk, 0, stream>>>(buf_s, sT16);
    gemm_bf16_bat<1><<<dim3(DM / 128, LSEQ / 128, BATCH), blk, 0, stream>>>(
        (const short*)wmid16, (const short*)sT16, (void*)t16, LSEQ, DM, LSEQ);

    // ---- Mamba 2 + LN2 ----
    mamba(t16, m2_Win, m2_convw, m2_convb, m2_Wx, m2_Wdt, m2_bdt, m2_Alog,
          m2_D, m2_Wout, buf_s);
    ln_kernel<<<dim3(NROWS), blk, 0, stream>>>(buf_s, ln2_g, ln2_b);

    // ---- residual path: buf_res = silu(x @ W_spa.T + b_spa) ----
    gemm_bf16_nt<2, 0><<<dim3(DM / 128, NROWS / 128), blk, 0, stream>>>(
        (const short*)bx, (const short*)wspa16, b_spa, buf_res,
        NROWS, DM, DM);
    // channel mix 2: d_out[b] = silu(W_res @ r[b]) via MFMA
    transpose_cast<<<dim3(32, 8, BATCH), blk, 0, stream>>>(buf_res, rT16);
    gemm_bf16_bat<0><<<dim3(DM / 128, LSEQ / 128, BATCH), blk, 0, stream>>>(
        (const short*)wres16, (const short*)rT16, d_out, LSEQ, DM, LSEQ);

    // ---- out = silu(s2 + r2) ----
    final_silu<<<dim3((NROWS * DM) / 256), blk, 0, stream>>>(
        buf_s, (float*)d_out);
}

// Round 5
// 459.663 us; speedup vs baseline: 3.1609x; 1.1569x over previous
//
#include <hip/hip_runtime.h>
#include <math.h>

// Problem constants (B=16, L=C=256 scan axis, dm=di=1024, n=2, dtr=64, k=4)
#define BATCH 16
#define LSEQ  256
#define DM    1024
#define DI    1024
#define NROWS (BATCH*LSEQ)   // 4096
#define DTR   64
#define TWO_DI 2048
#define NCH   16             // scan chunks
#define CHL   16             // chunk length (NCH*CHL == LSEQ)

typedef __attribute__((ext_vector_type(8))) short short8;
typedef __attribute__((ext_vector_type(4))) float floatx4;

__device__ __forceinline__ float siluf(float x) {
    return x / (1.0f + __expf(-x));
}
__device__ __forceinline__ float softplusf(float x) {
    return fmaxf(x, 0.0f) + log1pf(__expf(-fabsf(x)));
}
// fp32 -> bf16 (RNE), raw bits
__device__ __forceinline__ unsigned short f2bf(float f) {
    unsigned int u = __float_as_uint(f);
    u += 0x7fffu + ((u >> 16) & 1u);
    return (unsigned short)(u >> 16);
}
__device__ __forceinline__ float bf2f(unsigned short s) {
    return __uint_as_float(((unsigned int)s) << 16);
}
// async global->LDS, 16B per lane; LDS dest = wave-uniform base + lane*16
__device__ __forceinline__ void async16(const short* g, short* l) {
    __builtin_amdgcn_global_load_lds(
        (const __attribute__((address_space(1))) unsigned int*)g,
        (__attribute__((address_space(3))) unsigned int*)l,
        16, 0, 0);
}

// ---------------------------------------------------------------------------
// cast fp32 -> bf16, 4 elts/thread. n multiple of 1024.
// ---------------------------------------------------------------------------
__global__ __launch_bounds__(256) void cast_bf16(
    const float* __restrict__ in, unsigned short* __restrict__ out)
{
    const size_t i = ((size_t)blockIdx.x * 256 + threadIdx.x) * 4;
    const float4 v = *(const float4*)(in + i);
    union { unsigned short s[4]; unsigned long long u; } p;
    p.s[0] = f2bf(v.x); p.s[1] = f2bf(v.y);
    p.s[2] = f2bf(v.z); p.s[3] = f2bf(v.w);
    *(unsigned long long*)(out + i) = p.u;
}

// ---------------------------------------------------------------------------
// bf16 MFMA GEMM (nt), 64(M)x128(N) tile, double-buffered LDS.
// C[M,N] = A[M,K] @ W[N,K]^T. A,W bf16 row-major. M%64==0, N%128==0, K%32==0.
// 256 thr = 4 waves in 2x2 (wave: 32 rows x 64 cols, 2x4 16x16x32 frags).
// One barrier per K-iter; next tile's global_load_lds issued between the
// frag ds_reads and the MFMAs so load latency overlaps compute (1-2 blk/CU).
// EP: 0=none, 1=softplus(v+bias[c]), 2=silu(v+bias[c]), 3=silu(v)
// OUT16: 1 -> bf16 out, 0 -> fp32 out.  BATW: W,C batched by blockIdx.z.
// ---------------------------------------------------------------------------
template <int EP, int OUT16, int BATW>
__global__ __launch_bounds__(256) void gemm_bf16_nt(
    const short* __restrict__ A,
    const short* __restrict__ W,
    const float* __restrict__ bias,
    void* __restrict__ Cout,
    int M, int N, int K)
{
    __shared__ short As[2 * 64 * 32];    // [buf][m][k], 64 B rows
    __shared__ short Bs[2 * 128 * 32];   // [buf][n][k]

    const int bz = BATW ? blockIdx.z : 0;
    const short* Wb = W + (size_t)bz * N * K;
    const size_t cbase = (size_t)bz * M * N;

    const int tid  = threadIdx.x;
    const int wave = tid >> 6;
    const int lane = tid & 63;
    const int wm = wave >> 1;        // 0..1: row half (32 rows)
    const int wn = wave & 1;         // 0..1: col half (64 cols)
    const int row0 = blockIdx.y * 64;
    const int col0 = blockIdx.x * 128;

    // staging: 3 async16 per thread per tile (A:64 rows, B:128 rows)
    const int srow  = tid >> 2;          // 0..63
    const int skoff = (tid & 3) * 8;     // elt offset in k
    const short* gA  = A  + (size_t)(row0 + srow) * K + skoff;
    const short* gB0 = Wb + (size_t)(col0 + srow) * K + skoff;
    const short* gB1 = Wb + (size_t)(col0 + 64 + srow) * K + skoff;
    short* lA  = As + srow * 32 + skoff;
    short* lB0 = Bs + srow * 32 + skoff;
    short* lB1 = lB0 + 64 * 32;

    const int fr = lane & 15;
    const int fk = (lane >> 4) * 8;

    floatx4 acc[2][4] = {};

    // prologue: tile 0 -> buf 0
    async16(gA, lA);
    async16(gB0, lB0);
    async16(gB1, lB1);
    __syncthreads();

    int cur = 0;
    for (int k0 = 0; k0 < K; k0 += 32) {
        short8 af[2], bfr[4];
        const short* Ac = As + cur * 64 * 32;
        const short* Bc = Bs + cur * 128 * 32;
        #pragma unroll
        for (int i = 0; i < 2; i++)
            af[i] = *(const short8*)&Ac[(wm * 32 + i * 16 + fr) * 32 + fk];
        #pragma unroll
        for (int j = 0; j < 4; j++)
            bfr[j] = *(const short8*)&Bc[(wn * 64 + j * 16 + fr) * 32 + fk];

        if (k0 + 32 < K) {   // issue next tile into other buffer
            const int nb = (cur ^ 1);
            async16(gA + k0 + 32,  lA  + nb * 64 * 32);
            async16(gB0 + k0 + 32, lB0 + nb * 128 * 32);
            async16(gB1 + k0 + 32, lB1 + nb * 128 * 32);
        }

        #pragma unroll
        for (int i = 0; i < 2; i++)
            #pragma unroll
            for (int j = 0; j < 4; j++)
                acc[i][j] = __builtin_amdgcn_mfma_f32_16x16x32_bf16(
                    af[i], bfr[j], acc[i][j], 0, 0, 0);
        __syncthreads();
        cur ^= 1;
    }

    // C/D layout: col = lane&15, row = (lane>>4)*4 + r
    const int crow = row0 + wm * 32 + (lane >> 4) * 4;
    const int ccol = col0 + wn * 64 + (lane & 15);
    #pragma unroll
    for (int i = 0; i < 2; i++) {
        #pragma unroll
        for (int j = 0; j < 4; j++) {
            const int c = ccol + j * 16;
            #pragma unroll
            for (int r = 0; r < 4; r++) {
                float v = acc[i][j][r];
                if (EP == 1) v = softplusf(v + bias[c]);
                else if (EP == 2) v = siluf(v + bias[c]);
                else if (EP == 3) v = siluf(v);
                const size_t idx = cbase + (size_t)(crow + i * 16 + r) * N + c;
                if (OUT16) ((unsigned short*)Cout)[idx] = f2bf(v);
                else       ((float*)Cout)[idx] = v;
            }
        }
    }
}

// ---------------------------------------------------------------------------
// Wcomb = Wdt(1024x64) @ Wx[:64](64x1024), fp32 compute, bf16 out.
// ---------------------------------------------------------------------------
__global__ __launch_bounds__(256) void gemm_nn_wcomb(
    const float* __restrict__ Wdt,   // (1024, 64)
    const float* __restrict__ Wx,    // (68, 1024) - uses rows 0..63
    unsigned short* __restrict__ C16) // (1024, 1024) bf16
{
    __shared__ float Asf[16][64];
    __shared__ float Bsf[16][64];

    const int tid = threadIdx.x;
    const int tx = tid & 15;
    const int ty = tid >> 4;
    const int row0 = blockIdx.y * 64;
    const int col0 = blockIdx.x * 64;
    const int lrow = tid >> 2;
    const int lcol = (tid & 3) * 4;
    const int bk = tid >> 4;
    const int bn = (tid & 15) * 4;

    float acc[4][4] = {};

    for (int k0 = 0; k0 < 64; k0 += 16) {
        const float4 av = *(const float4*)(Wdt + (size_t)(row0 + lrow) * 64 + k0 + lcol);
        Asf[lcol + 0][lrow] = av.x;
        Asf[lcol + 1][lrow] = av.y;
        Asf[lcol + 2][lrow] = av.z;
        Asf[lcol + 3][lrow] = av.w;
        *(float4*)&Bsf[bk][bn] = *(const float4*)(Wx + (size_t)(k0 + bk) * 1024 + col0 + bn);
        __syncthreads();

        #pragma unroll
        for (int kk = 0; kk < 16; kk++) {
            const float4 a = *(const float4*)&Asf[kk][ty * 4];
            const float4 b = *(const float4*)&Bsf[kk][tx * 4];
            const float af[4] = {a.x, a.y, a.z, a.w};
            const float bfv[4] = {b.x, b.y, b.z, b.w};
            #pragma unroll
            for (int i = 0; i < 4; i++)
                #pragma unroll
                for (int j = 0; j < 4; j++)
                    acc[i][j] = fmaf(af[i], bfv[j], acc[i][j]);
        }
        __syncthreads();
    }

    #pragma unroll
    for (int i = 0; i < 4; i++) {
        const int r = row0 + ty * 4 + i;
        #pragma unroll
        for (int j = 0; j < 4; j++)
            C16[(size_t)r * 1024 + col0 + tx * 4 + j] = f2bf(acc[i][j]);
    }
}

// ---------------------------------------------------------------------------
// Depthwise causal conv (k=4) + bias + SiLU, fused B/C projection.
// Writes bf16 xi16 and bc[r][0..3] = xi_row . Wx[64+j].
// ---------------------------------------------------------------------------
__global__ __launch_bounds__(256) void conv_silu_bc(
    const float* __restrict__ xz,
    const float* __restrict__ convw,
    const float* __restrict__ convb,
    const float* __restrict__ Wx,     // (68, 1024): rows 64..67 = B0,B1,C0,C1
    unsigned short* __restrict__ xi16,
    float* __restrict__ bc)           // (4096, 4)
{
    __shared__ float redc[4][4];
    const int r = blockIdx.x;
    const int l = r & (LSEQ - 1);
    const int tid = threadIdx.x;
    float p0 = 0.f, p1 = 0.f, p2 = 0.f, p3 = 0.f;
    #pragma unroll
    for (int i = 0; i < 4; i++) {
        const int d = tid + i * 256;
        const float w0 = convw[d * 4 + 0];
        const float w1 = convw[d * 4 + 1];
        const float w2 = convw[d * 4 + 2];
        const float w3 = convw[d * 4 + 3];
        float acc = w3 * xz[(size_t)r * TWO_DI + d];
        if (l >= 1) acc = fmaf(w2, xz[(size_t)(r - 1) * TWO_DI + d], acc);
        if (l >= 2) acc = fmaf(w1, xz[(size_t)(r - 2) * TWO_DI + d], acc);
        if (l >= 3) acc = fmaf(w0, xz[(size_t)(r - 3) * TWO_DI + d], acc);
        const float v = siluf(acc + convb[d]);
        xi16[(size_t)r * DI + d] = f2bf(v);
        p0 = fmaf(v, Wx[64 * 1024 + d], p0);
        p1 = fmaf(v, Wx[65 * 1024 + d], p1);
        p2 = fmaf(v, Wx[66 * 1024 + d], p2);
        p3 = fmaf(v, Wx[67 * 1024 + d], p3);
    }
    #pragma unroll
    for (int o = 32; o; o >>= 1) {
        p0 += __shfl_down(p0, o, 64);
        p1 += __shfl_down(p1, o, 64);
        p2 += __shfl_down(p2, o, 64);
        p3 += __shfl_down(p3, o, 64);
    }
    const int w = tid >> 6, lane = tid & 63;
    if (lane == 0) {
        redc[w][0] = p0; redc[w][1] = p1; redc[w][2] = p2; redc[w][3] = p3;
    }
    __syncthreads();
    if (tid < 4)
        bc[r * 4 + tid] = redc[0][tid] + redc[1][tid] + redc[2][tid] + redc[3][tid];
}

// ---------------------------------------------------------------------------
// Chunked selective scan (n=2). NCH chunks of CHL steps.
// part1: per-chunk local end-state (h0,h1) and decay product (p0,p1), h(0)=0.
// ---------------------------------------------------------------------------
__global__ __launch_bounds__(256) void scan_part1(
    const unsigned short* __restrict__ dt16,
    const unsigned short* __restrict__ xi16,
    const float* __restrict__ bc,
    const float* __restrict__ Alog,
    float4* __restrict__ hc)          // (B, NCH, DI)
{
    const int d  = blockIdx.x * 256 + threadIdx.x;
    const int b  = blockIdx.y;
    const int ch = blockIdx.z;
    const float A0 = -__expf(Alog[d * 2 + 0]);
    const float A1 = -__expf(Alog[d * 2 + 1]);
    float h0 = 0.f, h1 = 0.f, p0 = 1.f, p1 = 1.f;
    const int r0 = b * LSEQ + ch * CHL;
    #pragma unroll 4
    for (int l = 0; l < CHL; l++) {
        const int r = r0 + l;
        const float dtv = bf2f(dt16[(size_t)r * DI + d]);
        const float xiv = bf2f(xi16[(size_t)r * DI + d]);
        const float4 bcv = *(const float4*)(bc + r * 4);
        const float e0 = __expf(dtv * A0);
        const float e1 = __expf(dtv * A1);
        const float dbx = dtv * xiv;
        h0 = fmaf(e0, h0, dbx * bcv.x);
        h1 = fmaf(e1, h1, dbx * bcv.y);
        p0 *= e0; p1 *= e1;
    }
    hc[(size_t)(b * NCH + ch) * DI + d] = make_float4(h0, h1, p0, p1);
}

// carry: sequential over chunks; writes carry-in state per chunk.
__global__ __launch_bounds__(256) void scan_carry(
    const float4* __restrict__ hc,
    float2* __restrict__ ci)          // (B, NCH, DI)
{
    const int d = blockIdx.x * 256 + threadIdx.x;
    const int b = blockIdx.y;
    float c0 = 0.f, c1 = 0.f;
    #pragma unroll
    for (int ch = 0; ch < NCH; ch++) {
        const size_t idx = (size_t)(b * NCH + ch) * DI + d;
        const float4 v = hc[idx];
        ci[idx] = make_float2(c0, c1);
        c0 = fmaf(v.z, c0, v.x);
        c1 = fmaf(v.w, c1, v.y);
    }
}

// part2: redo chunk recurrence seeded with carry; fused C-proj + D-skip + z-gate.
__global__ __launch_bounds__(256) void scan_part2(
    const unsigned short* __restrict__ dt16,
    const unsigned short* __restrict__ xi16,
    const float* __restrict__ xz,     // z = cols [1024,2048)
    const float* __restrict__ bc,
    const float* __restrict__ Alog,
    const float* __restrict__ Dp,
    const float2* __restrict__ ci,
    unsigned short* __restrict__ yg16)
{
    const int d  = blockIdx.x * 256 + threadIdx.x;
    const int b  = blockIdx.y;
    const int ch = blockIdx.z;
    const float A0 = -__expf(Alog[d * 2 + 0]);
    const float A1 = -__expf(Alog[d * 2 + 1]);
    const float Dv = Dp[d];
    const float2 c = ci[(size_t)(b * NCH + ch) * DI + d];
    float h0 = c.x, h1 = c.y;
    const int r0 = b * LSEQ + ch * CHL;
    #pragma unroll 4
    for (int l = 0; l < CHL; l++) {
        const int r = r0 + l;
        const float dtv = bf2f(dt16[(size_t)r * DI + d]);
        const float xiv = bf2f(xi16[(size_t)r * DI + d]);
        const float4 bcv = *(const float4*)(bc + r * 4);
        const float zv = xz[(size_t)r * TWO_DI + DI + d];
        const float e0 = __expf(dtv * A0);
        const float e1 = __expf(dtv * A1);
        const float dbx = dtv * xiv;
        h0 = fmaf(e0, h0, dbx * bcv.x);
        h1 = fmaf(e1, h1, dbx * bcv.y);
        const float y = fmaf(h0, bcv.z, fmaf(h1, bcv.w, Dv * xiv));
        yg16[(size_t)r * DI + d] = f2bf(y * siluf(zv));
    }
}

// ---------------------------------------------------------------------------
// LayerNorm over last dim (1024), in-place.
// ---------------------------------------------------------------------------
__global__ __launch_bounds__(256) void ln_kernel(
    float* __restrict__ s,
    const float* __restrict__ g,
    const float* __restrict__ bb)
{
    __shared__ float red[8];
    const size_t base = (size_t)blockIdx.x * DM;
    const int t = threadIdx.x;
    float x0 = s[base + t];
    float x1 = s[base + t + 256];
    float x2 = s[base + t + 512];
    float x3 = s[base + t + 768];
    float sum = x0 + x1 + x2 + x3;
    #pragma unroll
    for (int o = 32; o; o >>= 1) sum += __shfl_down(sum, o, 64);
    const int w = t >> 6, lane = t & 63;
    if (lane == 0) red[w] = sum;
    __syncthreads();
    const float m = (red[0] + red[1] + red[2] + red[3]) * (1.0f / 1024.0f);
    const float d0 = x0 - m, d1 = x1 - m, d2 = x2 - m, d3 = x3 - m;
    float ss = d0 * d0 + d1 * d1 + d2 * d2 + d3 * d3;
    #pragma unroll
    for (int o = 32; o; o >>= 1) ss += __shfl_down(ss, o, 64);
    if (lane == 0) red[4 + w] = ss;
    __syncthreads();
    const float var = (red[4] + red[5] + red[6] + red[7]) * (1.0f / 1024.0f);
    const float inv = rsqrtf(var + 1e-5f);
    s[base + t]       = d0 * inv * g[t]       + bb[t];
    s[base + t + 256] = d1 * inv * g[t + 256] + bb[t + 256];
    s[base + t + 512] = d2 * inv * g[t + 512] + bb[t + 512];
    s[base + t + 768] = d3 * inv * g[t + 768] + bb[t + 768];
}

// ---------------------------------------------------------------------------
// Per-batch transpose + cast: fp32 (b, 256 c, 1024 s) -> bf16 (b, 1024 s, 256 c)
// ---------------------------------------------------------------------------
__global__ __launch_bounds__(256) void transpose_cast(
    const float* __restrict__ in, unsigned short* __restrict__ out)
{
    __shared__ float tile[32][33];
    const int b = blockIdx.z;
    const int c0 = blockIdx.y * 32;
    const int s0 = blockIdx.x * 32;
    const int tx = threadIdx.x & 31;
    const int ty = threadIdx.x >> 5;   // 0..7
    const size_t ib = (size_t)b * 256 * 1024;
    const size_t ob = (size_t)b * 1024 * 256;
    #pragma unroll
    for (int i = 0; i < 4; i++)
        tile[tx][ty + i * 8] = in[ib + (size_t)(c0 + ty + i * 8) * 1024 + s0 + tx];
    __syncthreads();
    #pragma unroll
    for (int i = 0; i < 4; i++)
        out[ob + (size_t)(s0 + ty + i * 8) * 256 + c0 + tx] = f2bf(tile[ty + i * 8][tx]);
}

__global__ __launch_bounds__(256) void final_silu(
    const float* __restrict__ s, float* __restrict__ out)
{
    const size_t i = (size_t)blockIdx.x * 256 + threadIdx.x;
    out[i] = siluf(s[i] + out[i]);
}

// ---------------------------------------------------------------------------
extern "C" void kernel_launch(void* const* d_in, const int* in_sizes, int n_in,
                              void* d_out, int out_size, void* d_ws, size_t ws_size,
                              hipStream_t stream)
{
    const float* x        = (const float*)d_in[0];
    const float* m1_Win   = (const float*)d_in[1];
    const float* m1_convw = (const float*)d_in[2];
    const float* m1_convb = (const float*)d_in[3];
    const float* m1_Wx    = (const float*)d_in[4];
    const float* m1_Wdt   = (const float*)d_in[5];
    const float* m1_bdt   = (const float*)d_in[6];
    const float* m1_Alog  = (const float*)d_in[7];
    const float* m1_D     = (const float*)d_in[8];
    const float* m1_Wout  = (const float*)d_in[9];
    const float* m2_Win   = (const float*)d_in[10];
    const float* m2_convw = (const float*)d_in[11];
    const float* m2_convb = (const float*)d_in[12];
    const float* m2_Wx    = (const float*)d_in[13];
    const float* m2_Wdt   = (const float*)d_in[14];
    const float* m2_bdt   = (const float*)d_in[15];
    const float* m2_Alog  = (const float*)d_in[16];
    const float* m2_D     = (const float*)d_in[17];
    const float* m2_Wout  = (const float*)d_in[18];
    const float* ln1_g    = (const float*)d_in[19];
    const float* ln1_b    = (const float*)d_in[20];
    const float* ln2_g    = (const float*)d_in[21];
    const float* ln2_b    = (const float*)d_in[22];
    const float* W_mid    = (const float*)d_in[23];
    const float* W_spa    = (const float*)d_in[24];
    const float* b_spa    = (const float*)d_in[25];
    const float* W_res    = (const float*)d_in[26];

    float* ws = (float*)d_ws;
    size_t off = 0;
    float* buf_xz  = ws + off; off += (size_t)NROWS * TWO_DI;          // 32 MB
    float* buf_s   = ws + off; off += (size_t)NROWS * DI;              // 16 MB
    float* buf_bc  = ws + off; off += (size_t)NROWS * 4;
    float4* buf_hc = (float4*)(ws + off); off += (size_t)BATCH * NCH * DI * 4;  // 4 MB
    float2* buf_ci = (float2*)(ws + off); off += (size_t)BATCH * NCH * DI * 2;  // 2 MB
    unsigned short* bx     = (unsigned short*)(ws + off); off += (size_t)NROWS * DI / 2;
    unsigned short* xi16   = (unsigned short*)(ws + off); off += (size_t)NROWS * DI / 2;
    unsigned short* yg16   = (unsigned short*)(ws + off); off += (size_t)NROWS * DI / 2;
    unsigned short* sT16   = (unsigned short*)(ws + off); off += (size_t)NROWS * DI / 2;
    unsigned short* dt16   = (unsigned short*)(ws + off); off += (size_t)NROWS * DI / 2;
    unsigned short* win16  = (unsigned short*)(ws + off); off += (size_t)TWO_DI * DM / 2;
    unsigned short* wout16 = (unsigned short*)(ws + off); off += (size_t)DM * DI / 2;
    unsigned short* wspa16 = (unsigned short*)(ws + off); off += (size_t)DM * DM / 2;
    unsigned short* wcomb16= (unsigned short*)(ws + off); off += (size_t)DI * DI / 2;
    unsigned short* wmid16 = (unsigned short*)(ws + off); off += (size_t)LSEQ * LSEQ / 2;
    unsigned short* wres16 = (unsigned short*)(ws + off); off += (size_t)LSEQ * LSEQ / 2;
    unsigned short* t16 = yg16;    // mid-mix out / mamba2 in (lifetimes disjoint)
    float* buf_res = buf_xz;       // residual path after mamba2's scans done with xz
    unsigned short* rT16 = sT16;   // residual transpose after mid-mix done
    (void)ws_size; (void)n_in; (void)in_sizes; (void)out_size;

    const dim3 blk(256);

    auto mamba = [&](const unsigned short* inp16, const float* Win,
                     const float* convw, const float* convb, const float* Wx,
                     const float* Wdt, const float* bdt, const float* Alog,
                     const float* Dp, const float* Wout, float* out_buf) {
        cast_bf16<<<dim3((TWO_DI * DM) / 1024), blk, 0, stream>>>(Win, win16);
        cast_bf16<<<dim3((DM * DI) / 1024), blk, 0, stream>>>(Wout, wout16);
        // Wcomb = Wdt @ Wx[:64]  (1024,1024) bf16
        gemm_nn_wcomb<<<dim3(16, 16), blk, 0, stream>>>(Wdt, Wx, wcomb16);
        // xz = inp @ Win.T : (4096,2048)  [grid 16x64 = 1024 blocks]
        gemm_bf16_nt<0, 0, 0><<<dim3(TWO_DI / 128, NROWS / 64), blk, 0, stream>>>(
            (const short*)inp16, (const short*)win16, nullptr, buf_xz,
            NROWS, TWO_DI, DM);
        // conv + silu + fused B/C projection -> xi16, bc
        conv_silu_bc<<<dim3(NROWS), blk, 0, stream>>>(
            buf_xz, convw, convb, Wx, xi16, buf_bc);
        // dt16 = bf16(softplus(xi @ Wcomb.T + bdt))  [512 blocks]
        gemm_bf16_nt<1, 1, 0><<<dim3(DI / 128, NROWS / 64), blk, 0, stream>>>(
            (const short*)xi16, (const short*)wcomb16, bdt, dt16,
            NROWS, DI, DI);
        // chunked scan -> yg16
        scan_part1<<<dim3(DI / 256, BATCH, NCH), blk, 0, stream>>>(
            dt16, xi16, buf_bc, Alog, buf_hc);
        scan_carry<<<dim3(DI / 256, BATCH), blk, 0, stream>>>(buf_hc, buf_ci);
        scan_part2<<<dim3(DI / 256, BATCH, NCH), blk, 0, stream>>>(
            dt16, xi16, buf_xz, buf_bc, Alog, Dp, buf_ci, yg16);
        // out = yg @ Wout.T : (4096,1024)  [512 blocks]
        gemm_bf16_nt<0, 0, 0><<<dim3(DM / 128, NROWS / 64), blk, 0, stream>>>(
            (const short*)yg16, (const short*)wout16, nullptr, out_buf,
            NROWS, DM, DI);
    };

    // ---- casts of shared inputs ----
    cast_bf16<<<dim3((NROWS * DM) / 1024), blk, 0, stream>>>(x, bx);
    cast_bf16<<<dim3((DM * DM) / 1024), blk, 0, stream>>>(W_spa, wspa16);
    cast_bf16<<<dim3((LSEQ * LSEQ) / 1024), blk, 0, stream>>>(W_mid, wmid16);
    cast_bf16<<<dim3((LSEQ * LSEQ) / 1024), blk, 0, stream>>>(W_res, wres16);

    // ---- Mamba 1 + LN1 ----
    mamba(bx, m1_Win, m1_convw, m1_convb, m1_Wx, m1_Wdt, m1_bdt, m1_Alog, m1_D,
          m1_Wout, buf_s);
    ln_kernel<<<dim3(NROWS), blk, 0, stream>>>(buf_s, ln1_g, ln1_b);

    // ---- channel mix 1: t16[b] = bf16(silu(W_mid @ s[b])) via MFMA ----
    transpose_cast<<<dim3(32, 8, BATCH), blk, 0, stream>>>(buf_s, sT16);
    gemm_bf16_nt<3, 1, 1><<<dim3(DM / 128, LSEQ / 64, BATCH), blk, 0, stream>>>(
        (const short*)wmid16, (const short*)sT16, nullptr, (void*)t16,
        LSEQ, DM, LSEQ);

    // ---- Mamba 2 + LN2 ----
    mamba(t16, m2_Win, m2_convw, m2_convb, m2_Wx, m2_Wdt, m2_bdt, m2_Alog,
          m2_D, m2_Wout, buf_s);
    ln_kernel<<<dim3(NROWS), blk, 0, stream>>>(buf_s, ln2_g, ln2_b);

    // ---- residual path: buf_res = silu(x @ W_spa.T + b_spa)  [512 blocks] ----
    gemm_bf16_nt<2, 0, 0><<<dim3(DM / 128, NROWS / 64), blk, 0, stream>>>(
        (const short*)bx, (const short*)wspa16, b_spa, buf_res,
        NROWS, DM, DM);
    // channel mix 2: d_out[b] = silu(W_res @ r[b]) via MFMA
    transpose_cast<<<dim3(32, 8, BATCH), blk, 0, stream>>>(buf_res, rT16);
    gemm_bf16_nt<3, 0, 1><<<dim3(DM / 128, LSEQ / 64, BATCH), blk, 0, stream>>>(
        (const short*)wres16, (const short*)rT16, nullptr, d_out,
        LSEQ, DM, LSEQ);

    // ---- out = silu(s2 + r2) ----
    final_silu<<<dim3((NROWS * DM) / 256), blk, 0, stream>>>(
        buf_s, (float*)d_out);
}